// Round 3
// baseline (243.343 us; speedup 1.0000x reference)
//
#include <hip/hip_runtime.h>
#include <hip/hip_fp16.h>
#include <cstddef>

// ---------------------------------------------------------------------------
// CrossAttention, f16 MFMA, round 11.
//   B=2, Sq=Sk=2048, D=1024, H=16, Dh=64
// r10 post-mortem: barrier halving null; occupancy stuck at 18% because
// k-split holds 64 O-accs + 32 qB + 32 prefetch ≈ 190 regs/wave -> 256
// granule -> 2 waves/SIMD. r11: q-split (wave owns 16 q x all d, loops all
// k): O=16 accs, lp scalar (shfl reduce), qB=8 regs -> ~85 regs -> 128
// granule -> 4 waves/SIMD. Epilogue cross-wave O reduction eliminated.
// KVBLK=64 + Vs[64][72] kept (r10's [64][136] was +2M bank-conflict cyc).
// Layouts (16x16 MFMA): C/D col=lane&15, row=quad*4+reg.
//   x32 A/B: [idx=lane&15][k=quad*8+j (8)] ; x16 A/B: [idx=lane&15][k=quad*4+j]
// ---------------------------------------------------------------------------

#define B_   2
#define S_   2048
#define D_   1024
#define H_   16
#define DH_  64

typedef _Float16 half8 __attribute__((ext_vector_type(8)));
typedef _Float16 half4 __attribute__((ext_vector_type(4)));
typedef float floatx4 __attribute__((ext_vector_type(4)));

#define MFMA32(a, b, c) __builtin_amdgcn_mfma_f32_16x16x32_f16((a), (b), (c), 0, 0, 0)
#define MFMA16(a, b, c) __builtin_amdgcn_mfma_f32_16x16x16f16((a), (b), (c), 0, 0, 0)

// ---- fp32 -> f16, 3 tensors in one dispatch (y selects) ----
__global__ __launch_bounds__(256) void cvt3(
    const float* __restrict__ q, const float* __restrict__ k,
    const float* __restrict__ v,
    __half* __restrict__ qf, __half* __restrict__ kf, __half* __restrict__ vf)
{
    const float* srcs[3] = {q, k, v};
    __half* dsts[3] = {qf, kf, vf};
    const int z = blockIdx.y;
    const int i = blockIdx.x * 256 + threadIdx.x;
    const float4* s = (const float4*)srcs[z];
    const float4 a = s[2 * i], b = s[2 * i + 1];
    half8 h;
    h[0] = (_Float16)a.x; h[1] = (_Float16)a.y; h[2] = (_Float16)a.z; h[3] = (_Float16)a.w;
    h[4] = (_Float16)b.x; h[5] = (_Float16)b.y; h[6] = (_Float16)b.z; h[7] = (_Float16)b.w;
    *(half8*)&dsts[z][(size_t)i * 8] = h;
}

// ---- W [K][N] fp32 -> Wt [N][K] f16, 64x64 tiles, 4 weights via z ----
__global__ __launch_bounds__(256) void wtrans4(
    const float* __restrict__ Wq, const float* __restrict__ Wk,
    const float* __restrict__ Wv, const float* __restrict__ Wo,
    __half* __restrict__ Wtq, __half* __restrict__ Wtk,
    __half* __restrict__ Wtv, __half* __restrict__ Wto)
{
    __shared__ __align__(16) __half T[64][72];
    const float* Ws[4] = {Wq, Wk, Wv, Wo};
    __half* Wts[4] = {Wtq, Wtk, Wtv, Wto};
    const float* W = Ws[blockIdx.z];
    __half* Wt = Wts[blockIdx.z];
    const int tid = threadIdx.x;
    const int n0 = blockIdx.x * 64, k0 = blockIdx.y * 64;
    #pragma unroll
    for (int p = 0; p < 4; ++p) {
        const int c = tid + p * 256;
        const int kr = c >> 4, nc = (c & 15) * 4;
        const float4 a = *(const float4*)&W[(size_t)(k0 + kr) * D_ + n0 + nc];
        T[nc + 0][kr] = __float2half(a.x);
        T[nc + 1][kr] = __float2half(a.y);
        T[nc + 2][kr] = __float2half(a.z);
        T[nc + 3][kr] = __float2half(a.w);
    }
    __syncthreads();
    #pragma unroll
    for (int p = 0; p < 2; ++p) {
        const int c = tid + p * 256;
        const int nr = c >> 3, kc = (c & 7) * 8;
        *(half8*)&Wt[(size_t)(n0 + nr) * D_ + k0 + kc] = *(const half8*)&T[nr][kc];
    }
}

// ---- 128x128 f16 GEMM core, register-prefetch pipelined (r6 proven) ----
// mode 0: dst f16 scatter [B,H,S,Dh] * oscale (coalesced via LDS transpose)
// mode 1: dst fp32 [M][1024] direct
// mode 2: dst f16 transposed [B,H,Dh,S] (coalesced via LDS transpose)
__device__ __forceinline__ void gemm_core(
    const __half* __restrict__ A, const __half* __restrict__ Bt,
    const float* __restrict__ bias, void* __restrict__ dst,
    const int mode, const float oscale)
{
    __shared__ __align__(16) char gsm[36864];
    __half (*As)[72] = (__half(*)[72])gsm;
    __half (*Bs)[72] = (__half(*)[72])(gsm + 18432);

    const int tid = threadIdx.x;
    const int m0 = blockIdx.y * 128, n0 = blockIdx.x * 128;
    const int lane = tid & 63, wv = tid >> 6;
    const int quad = lane >> 4, lr = lane & 15;
    const int wm0 = (wv >> 1) * 64, wn0 = (wv & 1) * 64;

    floatx4 acc[4][4];
    #pragma unroll
    for (int i = 0; i < 4; ++i)
        #pragma unroll
        for (int j = 0; j < 4; ++j)
            acc[i][j] = (floatx4){0.f, 0.f, 0.f, 0.f};

    // prefetch k0 = 0 into registers
    half8 pa[4], pb[4];
    #pragma unroll
    for (int p = 0; p < 4; ++p) {
        const int c = tid + p * 256;
        const int row = c >> 3, seg = (c & 7) * 8;
        pa[p] = *(const half8*)&A [(size_t)(m0 + row) * D_ + seg];
        pb[p] = *(const half8*)&Bt[(size_t)(n0 + row) * D_ + seg];
    }

    for (int k0 = 0; k0 < D_; k0 += 64) {
        __syncthreads();                  // prev iter's LDS reads done
        #pragma unroll
        for (int p = 0; p < 4; ++p) {
            const int c = tid + p * 256;
            const int row = c >> 3, seg = (c & 7) * 8;
            *(half8*)&As[row][seg] = pa[p];
            *(half8*)&Bs[row][seg] = pb[p];
        }
        if (k0 + 64 < D_) {               // issue next tile's loads now;
            #pragma unroll                // they fly during the MFMA section
            for (int p = 0; p < 4; ++p) {
                const int c = tid + p * 256;
                const int row = c >> 3, seg = (c & 7) * 8;
                pa[p] = *(const half8*)&A [(size_t)(m0 + row) * D_ + k0 + 64 + seg];
                pb[p] = *(const half8*)&Bt[(size_t)(n0 + row) * D_ + k0 + 64 + seg];
            }
        }
        __syncthreads();                  // LDS tile visible
        #pragma unroll
        for (int ks = 0; ks < 2; ++ks) {
            const int ko = quad * 8 + ks * 32;
            half8 af[4], bf[4];
            #pragma unroll
            for (int i = 0; i < 4; ++i) af[i] = *(const half8*)&As[wm0 + i * 16 + lr][ko];
            #pragma unroll
            for (int j = 0; j < 4; ++j) bf[j] = *(const half8*)&Bs[wn0 + j * 16 + lr][ko];
            #pragma unroll
            for (int i = 0; i < 4; ++i)
                #pragma unroll
                for (int j = 0; j < 4; ++j)
                    acc[i][j] = MFMA32(af[i], bf[j], acc[i][j]);
        }
    }

    if (mode == 1) {
        float* out = (float*)dst;
        #pragma unroll
        for (int i = 0; i < 4; ++i) {
            #pragma unroll
            for (int j = 0; j < 4; ++j) {
                const int col = n0 + wn0 + j * 16 + lr;
                const float bval = bias[col];
                #pragma unroll
                for (int r = 0; r < 4; ++r) {
                    const int m = m0 + wm0 + i * 16 + quad * 4 + r;
                    out[(size_t)m * D_ + col] = acc[i][j][r] + bval;
                }
            }
        }
        return;
    }

    // ---- LDS transpose epilogue (modes 0 and 2) ----
    __syncthreads();
    __half (*Ct)[136] = (__half(*)[136])gsm;
    #pragma unroll
    for (int i = 0; i < 4; ++i) {
        #pragma unroll
        for (int j = 0; j < 4; ++j) {
            const int nl = wn0 + j * 16 + lr;
            const float bval = bias[n0 + nl];
            #pragma unroll
            for (int r = 0; r < 4; ++r) {
                const int ml = wm0 + i * 16 + quad * 4 + r;
                const _Float16 hv = (_Float16)((acc[i][j][r] + bval) * oscale);
                if (mode == 0) Ct[ml][nl] = hv;
                else           Ct[nl][ml] = hv;
            }
        }
    }
    __syncthreads();
    __half* oh = (__half*)dst;
    #pragma unroll
    for (int p = 0; p < 8; ++p) {
        const int row = (tid >> 4) + p * 16;
        const int cs  = (tid & 15) * 8;
        const half8 vls = *(const half8*)&Ct[row][cs];
        if (mode == 0) {
            const int m = m0 + row, col = n0 + cs;
            const int b = m >> 11, s = m & (S_ - 1);
            const int h = col >> 6, d = col & 63;
            *(half8*)&oh[(((size_t)(b * H_ + h) * S_ + s) << 6) + d] = vls;
        } else {
            const int col = n0 + row, m = m0 + cs;
            const int b = m >> 11, s = m & (S_ - 1);
            const int h = col >> 6, d = col & 63;
            *(half8*)&oh[((size_t)(b * H_ + h) * DH_ + d) * S_ + s] = vls;
        }
    }
}

// z=0: Q (scatter, *0.125*log2e for exp2 softmax), z=1: K, z=2: V (transposed)
__global__ __launch_bounds__(256) void gemm_proj(
    const __half* __restrict__ qf, const __half* __restrict__ kf,
    const __half* __restrict__ vf,
    const __half* __restrict__ Wtq, const __half* __restrict__ Wtk,
    const __half* __restrict__ Wtv,
    const float* __restrict__ bq, const float* __restrict__ bk,
    const float* __restrict__ bv,
    __half* __restrict__ qhf, __half* __restrict__ khf, __half* __restrict__ vht)
{
    const __half* As[3] = {qf, kf, vf};
    const __half* Bts[3] = {Wtq, Wtk, Wtv};
    const float* bs[3] = {bq, bk, bv};
    __half* ds[3] = {qhf, khf, vht};
    const int z = blockIdx.z;
    gemm_core(As[z], Bts[z], bs[z], ds[z], z == 2 ? 2 : 0,
              z == 0 ? 0.1803368801111244f : 1.0f);
}

__global__ __launch_bounds__(256) void gemm_final(
    const __half* __restrict__ attf, const __half* __restrict__ Wto,
    const float* __restrict__ bo, float* __restrict__ out)
{
    gemm_core(attf, Wto, bo, out, 1, 1.0f);
}

// ---- flash attention, q-split: wave owns 16 q-rows x all 64 d ----
// qhf/khf: [B,H,S,64] f16 (Q pre-scaled 0.125*log2e). vht: [B,H,64,S].
// Per 64-k tile per wave: 8 MFMA32 (S^T = K Q^T over 4 k-subtiles) +
// 16 exp2 + 16 MFMA16 (O^T += V^T P^T over 4 k-slices). O = 16 accs/lane;
// lp is a scalar reduced by shfl_xor(16/32). ~85 live regs -> cap 128 via
// launch_bounds(256,4) -> 4 waves/SIMD (r9's spill was 190 regs vs cap 128;
// now we have headroom).
__global__ __launch_bounds__(256, 4) void attn_f16(
    const __half* __restrict__ qhf, const __half* __restrict__ khf,
    const __half* __restrict__ vht, __half* __restrict__ attf)
{
    __shared__ __align__(16) char smem[18432];
    __half (*Ks)[72] = (__half(*)[72])smem;            // [64 k][64 d]
    __half (*Vs)[72] = (__half(*)[72])(smem + 9216);   // [64 d][64 s]

    const int tid = threadIdx.x;
    const int lane = tid & 63, wv = tid >> 6;
    const int quad = lane >> 4, lr = lane & 15;
    const int bh = blockIdx.y;
    const int q0 = blockIdx.x * 64;
    const size_t hbase = (size_t)bh * S_ * DH_;

    // ---- Q B-frags (x32 layout) for this wave's 16 q-rows, from global ----
    half8 qB[2];
    #pragma unroll
    for (int ks = 0; ks < 2; ++ks)
        qB[ks] = *(const half8*)&qhf[hbase
            + (size_t)(q0 + wv * 16 + lr) * DH_ + quad * 8 + ks * 32];

    float lp = 0.f;
    floatx4 O[4];      // O^T[d = ds*16+quad*4+r][q = wv*16+lr]
    #pragma unroll
    for (int i = 0; i < 4; ++i) O[i] = (floatx4){0.f, 0.f, 0.f, 0.f};

    // prefetch kt = 0
    half8 pk[2], pv[2];
    #pragma unroll
    for (int p = 0; p < 2; ++p) {
        const int c = tid + p * 256;
        const int row = c >> 3, seg = (c & 7) * 8;
        pk[p] = *(const half8*)&khf[hbase + (size_t)row * DH_ + seg];
        pv[p] = *(const half8*)&vht[hbase + (size_t)row * S_ + seg];
    }

    for (int kt = 0; kt < S_; kt += 64) {
        __syncthreads();                  // prev iter's LDS reads done
        #pragma unroll
        for (int p = 0; p < 2; ++p) {
            const int c = tid + p * 256;
            const int row = c >> 3, seg = (c & 7) * 8;
            *(half8*)&Ks[row][seg] = pk[p];
            *(half8*)&Vs[row][seg] = pv[p];
        }
        if (kt + 64 < S_) {               // next tile's loads fly during MFMA
            #pragma unroll
            for (int p = 0; p < 2; ++p) {
                const int c = tid + p * 256;
                const int row = c >> 3, seg = (c & 7) * 8;
                pk[p] = *(const half8*)&khf[hbase + (size_t)(kt + 64 + row) * DH_ + seg];
                pv[p] = *(const half8*)&vht[hbase + (size_t)row * S_ + kt + 64 + seg];
            }
        }
        __syncthreads();                  // staged tile visible

        // ---- S^T = K Q^T : all 64 k-rows x this wave's 16 q ----
        floatx4 s4[4];
        #pragma unroll
        for (int ksub = 0; ksub < 4; ++ksub) s4[ksub] = (floatx4){0.f, 0.f, 0.f, 0.f};
        #pragma unroll
        for (int ks = 0; ks < 2; ++ks) {
            #pragma unroll
            for (int ksub = 0; ksub < 4; ++ksub) {
                const half8 aK = *(const half8*)&Ks[ksub * 16 + lr][quad * 8 + ks * 32];
                s4[ksub] = MFMA32(aK, qB[ks], s4[ksub]);
            }
        }

        // ---- P^T = exp2(S^T); lp accumulates this lane's q-column sum ----
        half4 pB[4];
        #pragma unroll
        for (int ksub = 0; ksub < 4; ++ksub) {
            #pragma unroll
            for (int r = 0; r < 4; ++r) {
                const float p = __builtin_amdgcn_exp2f(s4[ksub][r]);
                lp += p;
                pB[ksub][r] = (_Float16)p;
            }
        }

        // ---- O^T += V^T P^T over all 4 k-slices ----
        #pragma unroll
        for (int ds = 0; ds < 4; ++ds) {
            #pragma unroll
            for (int ksl = 0; ksl < 4; ++ksl) {
                const half4 aV = *(const half4*)&Vs[ds * 16 + lr][ksl * 16 + quad * 4];
                O[ds] = MFMA16(aV, pB[ksl], O[ds]);
            }
        }
    }

    // ---- softmax denom: sum lp across the 4 quads (same q = lr) ----
    lp += __shfl_xor(lp, 16, 64);
    lp += __shfl_xor(lp, 32, 64);
    const float il = 1.0f / lp;

    // ---- scale, f16, stage to LDS for coalesced store ----
    __syncthreads();                               // all Ks/Vs reads done
    __half (*F)[72] = (__half(*)[72])smem;         // [64 q][64 d] overlay
    #pragma unroll
    for (int ds = 0; ds < 4; ++ds) {
        half4 hv;
        #pragma unroll
        for (int r = 0; r < 4; ++r) hv[r] = (_Float16)(O[ds][r] * il);
        *(half4*)&F[wv * 16 + lr][ds * 16 + quad * 4] = hv;
    }
    __syncthreads();

    const int b = bh >> 4, h = bh & 15;
    const int qrow = tid >> 2, dseg = (tid & 3) * 16;
    __half* dstp = &attf[(((size_t)(b * S_ + q0 + qrow)) << 10) + h * DH_ + dseg];
    *(half8*)&dstp[0] = *(const half8*)&F[qrow][dseg];
    *(half8*)&dstp[8] = *(const half8*)&F[qrow][dseg + 8];
}

extern "C" void kernel_launch(void* const* d_in, const int* in_sizes, int n_in,
                              void* d_out, int out_size, void* d_ws, size_t ws_size,
                              hipStream_t stream) {
    const float* q  = (const float*)d_in[0];
    const float* k  = (const float*)d_in[1];
    const float* v  = (const float*)d_in[2];
    const float* Wq = (const float*)d_in[3];
    const float* bq = (const float*)d_in[4];
    const float* Wk = (const float*)d_in[5];
    const float* bk = (const float*)d_in[6];
    const float* Wv = (const float*)d_in[7];
    const float* bv = (const float*)d_in[8];
    const float* Wo = (const float*)d_in[9];
    const float* bo = (const float*)d_in[10];
    float* out = (float*)d_out;

    __half* ws = (__half*)d_ws;
    const size_t NE = (size_t)B_ * S_ * D_;     // 4,194,304
    __half* qf   = ws;
    __half* kf   = ws + NE;
    __half* vf   = ws + 2 * NE;
    __half* qhf  = ws + 3 * NE;
    __half* khf  = ws + 4 * NE;
    __half* vht  = ws + 5 * NE;
    __half* attf = ws + 6 * NE;
    __half* Wtq  = ws + 7 * NE;
    __half* Wtk  = Wtq + (size_t)D_ * D_;
    __half* Wtv  = Wtk + (size_t)D_ * D_;
    __half* Wto  = Wtv + (size_t)D_ * D_;

    const dim3 blk(256);
    cvt3<<<dim3((unsigned)(NE / 8 / 256), 3), blk, 0, stream>>>(q, k, v, qf, kf, vf);
    wtrans4<<<dim3(16, 16, 4), blk, 0, stream>>>(Wq, Wk, Wv, Wo, Wtq, Wtk, Wtv, Wto);

    gemm_proj<<<dim3(D_ / 128, (B_ * S_) / 128, 3), blk, 0, stream>>>(
        qf, kf, vf, Wtq, Wtk, Wtv, bq, bk, bv, qhf, khf, vht);

    attn_f16<<<dim3(S_ / 64, B_ * H_), blk, 0, stream>>>(qhf, khf, vht, attf);

    gemm_final<<<dim3(D_ / 128, (B_ * S_) / 128), blk, 0, stream>>>(attf, Wto, bo, out);
}

// Round 4
// 239.717 us; speedup vs baseline: 1.0151x; 1.0151x over previous
//
#include <hip/hip_runtime.h>
#include <hip/hip_fp16.h>
#include <cstddef>

// ---------------------------------------------------------------------------
// CrossAttention, f16 MFMA, round 12.
//   B=2, Sq=Sk=2048, D=1024, H=16, Dh=64
// History: r8=63.8us attn (k-split KVBLK=64, 2 barriers/tile). r9 spill
// (launch_bounds cap). r10 KVBLK=128: barrier halving null. r11 q-split:
// occupancy 33% but 4x LDS read traffic -> 12.7M bank-conflict cyc, 70.7us.
// r12 = r8 structure + (a) LDS double-buffer: ONE barrier/tile, staging
// writes overlap compute reads (turnaround off critical path); (b) setprio(1)
// around MFMA clusters (m191: +4-7% attn); (c) aV reads hoisted before exp;
// (d) cvt3+wtrans4 fused into one prep dispatch.
// Layouts (16x16 MFMA): C/D col=lane&15, row=quad*4+reg.
//   x32 A/B: [idx=lane&15][k=quad*8+j (8)] ; x16 A/B: [idx=lane&15][k=quad*4+j]
// ---------------------------------------------------------------------------

#define B_   2
#define S_   2048
#define D_   1024
#define H_   16
#define DH_  64

typedef _Float16 half8 __attribute__((ext_vector_type(8)));
typedef _Float16 half4 __attribute__((ext_vector_type(4)));
typedef float floatx4 __attribute__((ext_vector_type(4)));

#define MFMA32(a, b, c) __builtin_amdgcn_mfma_f32_16x16x32_f16((a), (b), (c), 0, 0, 0)
#define MFMA16(a, b, c) __builtin_amdgcn_mfma_f32_16x16x16f16((a), (b), (c), 0, 0, 0)

// ---- fused: fp32->f16 cvt for q/k/v (z<3) + W transpose x4 (z==3) ----
__global__ __launch_bounds__(256) void prep(
    const float* __restrict__ q, const float* __restrict__ k,
    const float* __restrict__ v,
    __half* __restrict__ qf, __half* __restrict__ kf, __half* __restrict__ vf,
    const float* __restrict__ Wq, const float* __restrict__ Wk,
    const float* __restrict__ Wv, const float* __restrict__ Wo,
    __half* __restrict__ Wtq, __half* __restrict__ Wtk,
    __half* __restrict__ Wtv, __half* __restrict__ Wto)
{
    __shared__ __align__(16) __half T[64][72];
    const int tid = threadIdx.x;
    const int z = blockIdx.z;
    if (z < 3) {
        const float* srcs[3] = {q, k, v};
        __half* dsts[3] = {qf, kf, vf};
        const int i = blockIdx.x * 256 + tid;
        const float4* s = (const float4*)srcs[z];
        const float4 a = s[2 * i], b = s[2 * i + 1];
        half8 h;
        h[0] = (_Float16)a.x; h[1] = (_Float16)a.y; h[2] = (_Float16)a.z; h[3] = (_Float16)a.w;
        h[4] = (_Float16)b.x; h[5] = (_Float16)b.y; h[6] = (_Float16)b.z; h[7] = (_Float16)b.w;
        *(half8*)&dsts[z][(size_t)i * 8] = h;
        return;
    }
    if (blockIdx.x >= 256) return;
    const float* Ws[4] = {Wq, Wk, Wv, Wo};
    __half* Wts[4] = {Wtq, Wtk, Wtv, Wto};
    const int n0 = (blockIdx.x & 15) * 64, k0 = (blockIdx.x >> 4) * 64;
    for (int w = 0; w < 4; ++w) {
        const float* W = Ws[w];
        __half* Wt = Wts[w];
        #pragma unroll
        for (int p = 0; p < 4; ++p) {
            const int c = tid + p * 256;
            const int kr = c >> 4, nc = (c & 15) * 4;
            const float4 a = *(const float4*)&W[(size_t)(k0 + kr) * D_ + n0 + nc];
            T[nc + 0][kr] = __float2half(a.x);
            T[nc + 1][kr] = __float2half(a.y);
            T[nc + 2][kr] = __float2half(a.z);
            T[nc + 3][kr] = __float2half(a.w);
        }
        __syncthreads();
        #pragma unroll
        for (int p = 0; p < 2; ++p) {
            const int c = tid + p * 256;
            const int nr = c >> 3, kc = (c & 7) * 8;
            *(half8*)&Wt[(size_t)(n0 + nr) * D_ + k0 + kc] = *(const half8*)&T[nr][kc];
        }
        __syncthreads();
    }
}

// ---- 128x128 f16 GEMM core, register-prefetch pipelined (r6 proven) ----
// mode 0: dst f16 scatter [B,H,S,Dh] * oscale (coalesced via LDS transpose)
// mode 1: dst fp32 [M][1024] direct
// mode 2: dst f16 transposed [B,H,Dh,S] (coalesced via LDS transpose)
__device__ __forceinline__ void gemm_core(
    const __half* __restrict__ A, const __half* __restrict__ Bt,
    const float* __restrict__ bias, void* __restrict__ dst,
    const int mode, const float oscale)
{
    __shared__ __align__(16) char gsm[36864];
    __half (*As)[72] = (__half(*)[72])gsm;
    __half (*Bs)[72] = (__half(*)[72])(gsm + 18432);

    const int tid = threadIdx.x;
    const int m0 = blockIdx.y * 128, n0 = blockIdx.x * 128;
    const int lane = tid & 63, wv = tid >> 6;
    const int quad = lane >> 4, lr = lane & 15;
    const int wm0 = (wv >> 1) * 64, wn0 = (wv & 1) * 64;

    floatx4 acc[4][4];
    #pragma unroll
    for (int i = 0; i < 4; ++i)
        #pragma unroll
        for (int j = 0; j < 4; ++j)
            acc[i][j] = (floatx4){0.f, 0.f, 0.f, 0.f};

    // prefetch k0 = 0 into registers
    half8 pa[4], pb[4];
    #pragma unroll
    for (int p = 0; p < 4; ++p) {
        const int c = tid + p * 256;
        const int row = c >> 3, seg = (c & 7) * 8;
        pa[p] = *(const half8*)&A [(size_t)(m0 + row) * D_ + seg];
        pb[p] = *(const half8*)&Bt[(size_t)(n0 + row) * D_ + seg];
    }

    for (int k0 = 0; k0 < D_; k0 += 64) {
        __syncthreads();                  // prev iter's LDS reads done
        #pragma unroll
        for (int p = 0; p < 4; ++p) {
            const int c = tid + p * 256;
            const int row = c >> 3, seg = (c & 7) * 8;
            *(half8*)&As[row][seg] = pa[p];
            *(half8*)&Bs[row][seg] = pb[p];
        }
        if (k0 + 64 < D_) {               // issue next tile's loads now;
            #pragma unroll                // they fly during the MFMA section
            for (int p = 0; p < 4; ++p) {
                const int c = tid + p * 256;
                const int row = c >> 3, seg = (c & 7) * 8;
                pa[p] = *(const half8*)&A [(size_t)(m0 + row) * D_ + k0 + 64 + seg];
                pb[p] = *(const half8*)&Bt[(size_t)(n0 + row) * D_ + k0 + 64 + seg];
            }
        }
        __syncthreads();                  // LDS tile visible
        #pragma unroll
        for (int ks = 0; ks < 2; ++ks) {
            const int ko = quad * 8 + ks * 32;
            half8 af[4], bf[4];
            #pragma unroll
            for (int i = 0; i < 4; ++i) af[i] = *(const half8*)&As[wm0 + i * 16 + lr][ko];
            #pragma unroll
            for (int j = 0; j < 4; ++j) bf[j] = *(const half8*)&Bs[wn0 + j * 16 + lr][ko];
            #pragma unroll
            for (int i = 0; i < 4; ++i)
                #pragma unroll
                for (int j = 0; j < 4; ++j)
                    acc[i][j] = MFMA32(af[i], bf[j], acc[i][j]);
        }
    }

    if (mode == 1) {
        float* out = (float*)dst;
        #pragma unroll
        for (int i = 0; i < 4; ++i) {
            #pragma unroll
            for (int j = 0; j < 4; ++j) {
                const int col = n0 + wn0 + j * 16 + lr;
                const float bval = bias[col];
                #pragma unroll
                for (int r = 0; r < 4; ++r) {
                    const int m = m0 + wm0 + i * 16 + quad * 4 + r;
                    out[(size_t)m * D_ + col] = acc[i][j][r] + bval;
                }
            }
        }
        return;
    }

    // ---- LDS transpose epilogue (modes 0 and 2) ----
    __syncthreads();
    __half (*Ct)[136] = (__half(*)[136])gsm;
    #pragma unroll
    for (int i = 0; i < 4; ++i) {
        #pragma unroll
        for (int j = 0; j < 4; ++j) {
            const int nl = wn0 + j * 16 + lr;
            const float bval = bias[n0 + nl];
            #pragma unroll
            for (int r = 0; r < 4; ++r) {
                const int ml = wm0 + i * 16 + quad * 4 + r;
                const _Float16 hv = (_Float16)((acc[i][j][r] + bval) * oscale);
                if (mode == 0) Ct[ml][nl] = hv;
                else           Ct[nl][ml] = hv;
            }
        }
    }
    __syncthreads();
    __half* oh = (__half*)dst;
    #pragma unroll
    for (int p = 0; p < 8; ++p) {
        const int row = (tid >> 4) + p * 16;
        const int cs  = (tid & 15) * 8;
        const half8 vls = *(const half8*)&Ct[row][cs];
        if (mode == 0) {
            const int m = m0 + row, col = n0 + cs;
            const int b = m >> 11, s = m & (S_ - 1);
            const int h = col >> 6, d = col & 63;
            *(half8*)&oh[(((size_t)(b * H_ + h) * S_ + s) << 6) + d] = vls;
        } else {
            const int col = n0 + row, m = m0 + cs;
            const int b = m >> 11, s = m & (S_ - 1);
            const int h = col >> 6, d = col & 63;
            *(half8*)&oh[((size_t)(b * H_ + h) * DH_ + d) * S_ + s] = vls;
        }
    }
}

// z=0: Q (scatter, *0.125*log2e for exp2 softmax), z=1: K, z=2: V (transposed)
__global__ __launch_bounds__(256) void gemm_proj(
    const __half* __restrict__ qf, const __half* __restrict__ kf,
    const __half* __restrict__ vf,
    const __half* __restrict__ Wtq, const __half* __restrict__ Wtk,
    const __half* __restrict__ Wtv,
    const float* __restrict__ bq, const float* __restrict__ bk,
    const float* __restrict__ bv,
    __half* __restrict__ qhf, __half* __restrict__ khf, __half* __restrict__ vht)
{
    const __half* As[3] = {qf, kf, vf};
    const __half* Bts[3] = {Wtq, Wtk, Wtv};
    const float* bs[3] = {bq, bk, bv};
    __half* ds[3] = {qhf, khf, vht};
    const int z = blockIdx.z;
    gemm_core(As[z], Bts[z], bs[z], ds[z], z == 2 ? 2 : 0,
              z == 0 ? 0.1803368801111244f : 1.0f);
}

__global__ __launch_bounds__(256) void gemm_final(
    const __half* __restrict__ attf, const __half* __restrict__ Wto,
    const float* __restrict__ bo, float* __restrict__ out)
{
    gemm_core(attf, Wto, bo, out, 1, 1.0f);
}

// ---- flash attention, k-split, LDS double-buffered: ONE barrier/tile ----
// qhf/khf: [B,H,S,64] f16 (Q pre-scaled 0.125*log2e). vht: [B,H,64,S].
// buf b: K at smem+b*18432 [64][72], V at smem+b*18432+9216 [64][72].
// Loop t: write tile t+1 into buf^1 (from regs) || compute tile t from buf;
// issue t+2 global loads; single barrier. Writes never touch the buffer
// being read; the end-of-iter barrier orders write->read (t+1) and
// read->overwrite (t+2).
__global__ __launch_bounds__(256) void attn_f16(
    const __half* __restrict__ qhf, const __half* __restrict__ khf,
    const __half* __restrict__ vht, __half* __restrict__ attf)
{
    __shared__ __align__(16) char smem[36864];

    const int tid = threadIdx.x;
    const int lane = tid & 63, wv = tid >> 6;
    const int quad = lane >> 4, lr = lane & 15;
    const int bh = blockIdx.y;
    const int q0 = blockIdx.x * 64;
    const size_t hbase = (size_t)bh * S_ * DH_;

    // ---- Q B-frags (x32 layout) straight from global (r10-verified) ----
    half8 qB[4][2];
    #pragma unroll
    for (int qs = 0; qs < 4; ++qs)
        #pragma unroll
        for (int ks = 0; ks < 2; ++ks)
            qB[qs][ks] = *(const half8*)&qhf[hbase
                + (size_t)(q0 + qs * 16 + lr) * DH_ + quad * 8 + ks * 32];

    float lp[4] = {0.f, 0.f, 0.f, 0.f};
    floatx4 O[4][4];   // [dsub][qsub] partial O^T over this wave's k-slice
    #pragma unroll
    for (int i = 0; i < 4; ++i)
        #pragma unroll
        for (int j = 0; j < 4; ++j)
            O[i][j] = (floatx4){0.f, 0.f, 0.f, 0.f};

    // ---- stage tile 0 directly into buf0 ----
    {
        __half (*K0)[72] = (__half(*)[72])smem;
        __half (*V0)[72] = (__half(*)[72])(smem + 9216);
        #pragma unroll
        for (int p = 0; p < 2; ++p) {
            const int c = tid + p * 256;
            const int row = c >> 3, seg = (c & 7) * 8;
            *(half8*)&K0[row][seg] = *(const half8*)&khf[hbase + (size_t)row * DH_ + seg];
            *(half8*)&V0[row][seg] = *(const half8*)&vht[hbase + (size_t)row * S_ + seg];
        }
    }
    // ---- prefetch tile 1 into registers ----
    half8 pk[2], pv[2];
    #pragma unroll
    for (int p = 0; p < 2; ++p) {
        const int c = tid + p * 256;
        const int row = c >> 3, seg = (c & 7) * 8;
        pk[p] = *(const half8*)&khf[hbase + (size_t)(64 + row) * DH_ + seg];
        pv[p] = *(const half8*)&vht[hbase + (size_t)row * S_ + 64 + seg];
    }
    __syncthreads();                       // tile 0 visible

    for (int kt = 0; kt < S_; kt += 64) {
        const int cb = (kt >> 6) & 1;
        __half (*Ks)[72] = (__half(*)[72])(smem + cb * 18432);
        __half (*Vs)[72] = (__half(*)[72])(smem + cb * 18432 + 9216);
        __half (*Kn)[72] = (__half(*)[72])(smem + (cb ^ 1) * 18432);
        __half (*Vn)[72] = (__half(*)[72])(smem + (cb ^ 1) * 18432 + 9216);

        // write tile t+1 into the other buffer (overlaps compute reads)
        if (kt + 64 < S_) {
            #pragma unroll
            for (int p = 0; p < 2; ++p) {
                const int c = tid + p * 256;
                const int row = c >> 3, seg = (c & 7) * 8;
                *(half8*)&Kn[row][seg] = pk[p];
                *(half8*)&Vn[row][seg] = pv[p];
            }
            if (kt + 128 < S_) {           // issue t+2 loads; fly during compute
                #pragma unroll
                for (int p = 0; p < 2; ++p) {
                    const int c = tid + p * 256;
                    const int row = c >> 3, seg = (c & 7) * 8;
                    pk[p] = *(const half8*)&khf[hbase + (size_t)(kt + 128 + row) * DH_ + seg];
                    pv[p] = *(const half8*)&vht[hbase + (size_t)row * S_ + kt + 128 + seg];
                }
            }
        }

        // ---- S^T = K Q^T : wave owns k-rows wv*16..+15, all 64 q ----
        floatx4 s4[4];
        #pragma unroll
        for (int qs = 0; qs < 4; ++qs) s4[qs] = (floatx4){0.f, 0.f, 0.f, 0.f};
        __builtin_amdgcn_s_setprio(1);
        #pragma unroll
        for (int ks = 0; ks < 2; ++ks) {
            const half8 aK = *(const half8*)&Ks[wv * 16 + lr][quad * 8 + ks * 32];
            #pragma unroll
            for (int qs = 0; qs < 4; ++qs)
                s4[qs] = MFMA32(aK, qB[qs][ks], s4[qs]);
        }
        __builtin_amdgcn_s_setprio(0);

        // ---- aV hoisted: lgkm latency hides under the exp section ----
        half4 aV[4];
        #pragma unroll
        for (int ds = 0; ds < 4; ++ds)
            aV[ds] = *(const half4*)&Vs[ds * 16 + lr][wv * 16 + quad * 4];

        // ---- P^T = exp2(S^T) via raw v_exp_f32; partial col sums ----
        half4 pB[4];
        #pragma unroll
        for (int qs = 0; qs < 4; ++qs) {
            #pragma unroll
            for (int r = 0; r < 4; ++r) {
                const float p = __builtin_amdgcn_exp2f(s4[qs][r]);
                lp[qs] += p;
                pB[qs][r] = (_Float16)p;
            }
        }

        // ---- O^T += V^T P^T over wave's 16-k slice (x16) ----
        __builtin_amdgcn_s_setprio(1);
        #pragma unroll
        for (int ds = 0; ds < 4; ++ds)
            #pragma unroll
            for (int qs = 0; qs < 4; ++qs)
                O[ds][qs] = MFMA16(aV[ds], pB[qs], O[ds][qs]);
        __builtin_amdgcn_s_setprio(0);

        __syncthreads();   // t+1 writes visible; reads of buf done before t+2 overwrite
    }

    // ---- cross-wave reduction (overlay buffers; all K/V reads done) ----
    float* L    = (float*)(smem + 17408);      // [16][64]
    float* invL = (float*)(smem + 21504);      // [64]
    float (*R)[68] = (float(*)[68])smem;       // [64][68]
    __half (*F)[72] = (__half(*)[72])(smem + 22016);  // [64 q][64 d]

    #pragma unroll
    for (int qs = 0; qs < 4; ++qs)
        L[(wv * 4 + quad) * 64 + qs * 16 + lr] = lp[qs];
    __syncthreads();
    if (tid < 64) {
        float s = 0.f;
        #pragma unroll
        for (int i = 0; i < 16; ++i) s += L[i * 64 + tid];
        invL[tid] = 1.0f / s;
    }
    __syncthreads();

    const int qc = tid & 63, dg = tid >> 6;
    const float il = invL[qc];

    #pragma unroll
    for (int ds = 0; ds < 4; ++ds) {
        __syncthreads();
        #pragma unroll
        for (int qs = 0; qs < 4; ++qs)
            #pragma unroll
            for (int r = 0; r < 4; ++r)
                R[wv * 16 + quad * 4 + r][qs * 16 + lr] = O[ds][qs][r];
        __syncthreads();
        half4 hv;
        #pragma unroll
        for (int rr = 0; rr < 4; ++rr) {
            const int row = dg * 4 + rr;
            const float v = R[row][qc] + R[16 + row][qc] + R[32 + row][qc] + R[48 + row][qc];
            hv[rr] = (_Float16)(v * il);
        }
        *(half4*)&F[qc][ds * 16 + dg * 4] = hv;
    }
    __syncthreads();

    const int b = bh >> 4, h = bh & 15;
    const int qrow = tid >> 2, dseg = (tid & 3) * 16;
    __half* dstp = &attf[(((size_t)(b * S_ + q0 + qrow)) << 10) + h * DH_ + dseg];
    *(half8*)&dstp[0] = *(const half8*)&F[qrow][dseg];
    *(half8*)&dstp[8] = *(const half8*)&F[qrow][dseg + 8];
}

extern "C" void kernel_launch(void* const* d_in, const int* in_sizes, int n_in,
                              void* d_out, int out_size, void* d_ws, size_t ws_size,
                              hipStream_t stream) {
    const float* q  = (const float*)d_in[0];
    const float* k  = (const float*)d_in[1];
    const float* v  = (const float*)d_in[2];
    const float* Wq = (const float*)d_in[3];
    const float* bq = (const float*)d_in[4];
    const float* Wk = (const float*)d_in[5];
    const float* bk = (const float*)d_in[6];
    const float* Wv = (const float*)d_in[7];
    const float* bv = (const float*)d_in[8];
    const float* Wo = (const float*)d_in[9];
    const float* bo = (const float*)d_in[10];
    float* out = (float*)d_out;

    __half* ws = (__half*)d_ws;
    const size_t NE = (size_t)B_ * S_ * D_;     // 4,194,304
    __half* qf   = ws;
    __half* kf   = ws + NE;
    __half* vf   = ws + 2 * NE;
    __half* qhf  = ws + 3 * NE;
    __half* khf  = ws + 4 * NE;
    __half* vht  = ws + 5 * NE;
    __half* attf = ws + 6 * NE;
    __half* Wtq  = ws + 7 * NE;
    __half* Wtk  = Wtq + (size_t)D_ * D_;
    __half* Wtv  = Wtk + (size_t)D_ * D_;
    __half* Wto  = Wtv + (size_t)D_ * D_;

    const dim3 blk(256);
    prep<<<dim3((unsigned)(NE / 8 / 256), 1, 4), blk, 0, stream>>>(
        q, k, v, qf, kf, vf, Wq, Wk, Wv, Wo, Wtq, Wtk, Wtv, Wto);

    gemm_proj<<<dim3(D_ / 128, (B_ * S_) / 128, 3), blk, 0, stream>>>(
        qf, kf, vf, Wtq, Wtk, Wtv, bq, bk, bv, qhf, khf, vht);

    attn_f16<<<dim3(S_ / 64, B_ * H_), blk, 0, stream>>>(qhf, khf, vht, attf);

    gemm_final<<<dim3(D_ / 128, (B_ * S_) / 128), blk, 0, stream>>>(attf, Wto, bo, out);
}

// Round 5
// 229.633 us; speedup vs baseline: 1.0597x; 1.0439x over previous
//
#include <hip/hip_runtime.h>
#include <hip/hip_fp16.h>
#include <cstddef>

// ---------------------------------------------------------------------------
// CrossAttention, f16 MFMA, round 13.
//   B=2, Sq=Sk=2048, D=1024, H=16, Dh=64
// r10/r11/r12 post-mortems: barriers, occupancy, staging all null; bottleneck
// is per-wave compute issue cost: x16 PV MFMAs at half rate + ~50 scalar
// cvt/insert VALU ops per tile building P half4s.
// r13: 32x32x16 MFMAs (4096 FLOP/cyc) for QK and PV + T12 in-register P
// repack: 8 v_cvt_pkrtz + 4 permlane32_swap per tile. Wave owns
// (k-band=wv>>1, q-band=wv&1) 32x32 subtile. O accs 64->32 regs ->
// launch_bounds(256,4) now safe (~113 live regs vs cap 128) -> 4 waves/SIMD.
// Layouts (32x32x16): A/B [idx=lane&31][k=(lane>>5)*8+j];
//   C/D col=lane&31, row=(reg&3)+8*(reg>>2)+4*(lane>>5)  [m74/m101].
// P repack (derived, both lane halves get same reg order):
//   P0=pk(s0,s1) P1=pk(s2,s3) P2=pk(s4,s5) P3=pk(s6,s7);
//   swap(P0,P2), swap(P1,P3) -> B-frag words [P0,P1,P2,P3].
// ---------------------------------------------------------------------------

#define B_   2
#define S_   2048
#define D_   1024
#define H_   16
#define DH_  64

typedef _Float16 half8 __attribute__((ext_vector_type(8)));
typedef _Float16 half4 __attribute__((ext_vector_type(4)));
typedef float floatx4 __attribute__((ext_vector_type(4)));
typedef float floatx16 __attribute__((ext_vector_type(16)));
typedef int intx4 __attribute__((ext_vector_type(4)));

#define MFMA32(a, b, c) __builtin_amdgcn_mfma_f32_16x16x32_f16((a), (b), (c), 0, 0, 0)
#define MFMA3216(a, b, c) __builtin_amdgcn_mfma_f32_32x32x16_f16((a), (b), (c), 0, 0, 0)

// exchange: newA = {A.lo32, B.lo32}, newB = {A.hi32, B.hi32}
__device__ __forceinline__ void half_swap(int& a, int& b, const int hi) {
#if __has_builtin(__builtin_amdgcn_permlane32_swap)
    (void)hi;
    auto r = __builtin_amdgcn_permlane32_swap(a, b, false, false);
    a = r[0]; b = r[1];
#else
    const int ax = __shfl_xor(a, 32, 64), bx = __shfl_xor(b, 32, 64);
    const int na = hi ? bx : a;
    b = hi ? b : ax;
    a = na;
#endif
}

// ---- fused: fp32->f16 cvt for q/k/v (z<3) + W transpose x4 (z==3) ----
__global__ __launch_bounds__(256) void prep(
    const float* __restrict__ q, const float* __restrict__ k,
    const float* __restrict__ v,
    __half* __restrict__ qf, __half* __restrict__ kf, __half* __restrict__ vf,
    const float* __restrict__ Wq, const float* __restrict__ Wk,
    const float* __restrict__ Wv, const float* __restrict__ Wo,
    __half* __restrict__ Wtq, __half* __restrict__ Wtk,
    __half* __restrict__ Wtv, __half* __restrict__ Wto)
{
    __shared__ __align__(16) __half T[64][72];
    const int tid = threadIdx.x;
    const int z = blockIdx.z;
    if (z < 3) {
        const float* srcs[3] = {q, k, v};
        __half* dsts[3] = {qf, kf, vf};
        const int i = blockIdx.x * 256 + tid;
        const float4* s = (const float4*)srcs[z];
        const float4 a = s[2 * i], b = s[2 * i + 1];
        half8 h;
        h[0] = (_Float16)a.x; h[1] = (_Float16)a.y; h[2] = (_Float16)a.z; h[3] = (_Float16)a.w;
        h[4] = (_Float16)b.x; h[5] = (_Float16)b.y; h[6] = (_Float16)b.z; h[7] = (_Float16)b.w;
        *(half8*)&dsts[z][(size_t)i * 8] = h;
        return;
    }
    if (blockIdx.x >= 256) return;
    const float* Ws[4] = {Wq, Wk, Wv, Wo};
    __half* Wts[4] = {Wtq, Wtk, Wtv, Wto};
    const int n0 = (blockIdx.x & 15) * 64, k0 = (blockIdx.x >> 4) * 64;
    for (int w = 0; w < 4; ++w) {
        const float* W = Ws[w];
        __half* Wt = Wts[w];
        #pragma unroll
        for (int p = 0; p < 4; ++p) {
            const int c = tid + p * 256;
            const int kr = c >> 4, nc = (c & 15) * 4;
            const float4 a = *(const float4*)&W[(size_t)(k0 + kr) * D_ + n0 + nc];
            T[nc + 0][kr] = __float2half(a.x);
            T[nc + 1][kr] = __float2half(a.y);
            T[nc + 2][kr] = __float2half(a.z);
            T[nc + 3][kr] = __float2half(a.w);
        }
        __syncthreads();
        #pragma unroll
        for (int p = 0; p < 2; ++p) {
            const int c = tid + p * 256;
            const int nr = c >> 3, kc = (c & 7) * 8;
            *(half8*)&Wt[(size_t)(n0 + nr) * D_ + k0 + kc] = *(const half8*)&T[nr][kc];
        }
        __syncthreads();
    }
}

// ---- 128x128 f16 GEMM core, register-prefetch pipelined (r6 proven) ----
// mode 0: dst f16 scatter [B,H,S,Dh] * oscale (coalesced via LDS transpose)
// mode 1: dst fp32 [M][1024] direct
// mode 2: dst f16 transposed [B,H,Dh,S] (coalesced via LDS transpose)
__device__ __forceinline__ void gemm_core(
    const __half* __restrict__ A, const __half* __restrict__ Bt,
    const float* __restrict__ bias, void* __restrict__ dst,
    const int mode, const float oscale)
{
    __shared__ __align__(16) char gsm[36864];
    __half (*As)[72] = (__half(*)[72])gsm;
    __half (*Bs)[72] = (__half(*)[72])(gsm + 18432);

    const int tid = threadIdx.x;
    const int m0 = blockIdx.y * 128, n0 = blockIdx.x * 128;
    const int lane = tid & 63, wv = tid >> 6;
    const int quad = lane >> 4, lr = lane & 15;
    const int wm0 = (wv >> 1) * 64, wn0 = (wv & 1) * 64;

    floatx4 acc[4][4];
    #pragma unroll
    for (int i = 0; i < 4; ++i)
        #pragma unroll
        for (int j = 0; j < 4; ++j)
            acc[i][j] = (floatx4){0.f, 0.f, 0.f, 0.f};

    // prefetch k0 = 0 into registers
    half8 pa[4], pb[4];
    #pragma unroll
    for (int p = 0; p < 4; ++p) {
        const int c = tid + p * 256;
        const int row = c >> 3, seg = (c & 7) * 8;
        pa[p] = *(const half8*)&A [(size_t)(m0 + row) * D_ + seg];
        pb[p] = *(const half8*)&Bt[(size_t)(n0 + row) * D_ + seg];
    }

    for (int k0 = 0; k0 < D_; k0 += 64) {
        __syncthreads();                  // prev iter's LDS reads done
        #pragma unroll
        for (int p = 0; p < 4; ++p) {
            const int c = tid + p * 256;
            const int row = c >> 3, seg = (c & 7) * 8;
            *(half8*)&As[row][seg] = pa[p];
            *(half8*)&Bs[row][seg] = pb[p];
        }
        if (k0 + 64 < D_) {               // issue next tile's loads now;
            #pragma unroll                // they fly during the MFMA section
            for (int p = 0; p < 4; ++p) {
                const int c = tid + p * 256;
                const int row = c >> 3, seg = (c & 7) * 8;
                pa[p] = *(const half8*)&A [(size_t)(m0 + row) * D_ + k0 + 64 + seg];
                pb[p] = *(const half8*)&Bt[(size_t)(n0 + row) * D_ + k0 + 64 + seg];
            }
        }
        __syncthreads();                  // LDS tile visible
        #pragma unroll
        for (int ks = 0; ks < 2; ++ks) {
            const int ko = quad * 8 + ks * 32;
            half8 af[4], bf[4];
            #pragma unroll
            for (int i = 0; i < 4; ++i) af[i] = *(const half8*)&As[wm0 + i * 16 + lr][ko];
            #pragma unroll
            for (int j = 0; j < 4; ++j) bf[j] = *(const half8*)&Bs[wn0 + j * 16 + lr][ko];
            #pragma unroll
            for (int i = 0; i < 4; ++i)
                #pragma unroll
                for (int j = 0; j < 4; ++j)
                    acc[i][j] = MFMA32(af[i], bf[j], acc[i][j]);
        }
    }

    if (mode == 1) {
        float* out = (float*)dst;
        #pragma unroll
        for (int i = 0; i < 4; ++i) {
            #pragma unroll
            for (int j = 0; j < 4; ++j) {
                const int col = n0 + wn0 + j * 16 + lr;
                const float bval = bias[col];
                #pragma unroll
                for (int r = 0; r < 4; ++r) {
                    const int m = m0 + wm0 + i * 16 + quad * 4 + r;
                    out[(size_t)m * D_ + col] = acc[i][j][r] + bval;
                }
            }
        }
        return;
    }

    // ---- LDS transpose epilogue (modes 0 and 2) ----
    __syncthreads();
    __half (*Ct)[136] = (__half(*)[136])gsm;
    #pragma unroll
    for (int i = 0; i < 4; ++i) {
        #pragma unroll
        for (int j = 0; j < 4; ++j) {
            const int nl = wn0 + j * 16 + lr;
            const float bval = bias[n0 + nl];
            #pragma unroll
            for (int r = 0; r < 4; ++r) {
                const int ml = wm0 + i * 16 + quad * 4 + r;
                const _Float16 hv = (_Float16)((acc[i][j][r] + bval) * oscale);
                if (mode == 0) Ct[ml][nl] = hv;
                else           Ct[nl][ml] = hv;
            }
        }
    }
    __syncthreads();
    __half* oh = (__half*)dst;
    #pragma unroll
    for (int p = 0; p < 8; ++p) {
        const int row = (tid >> 4) + p * 16;
        const int cs  = (tid & 15) * 8;
        const half8 vls = *(const half8*)&Ct[row][cs];
        if (mode == 0) {
            const int m = m0 + row, col = n0 + cs;
            const int b = m >> 11, s = m & (S_ - 1);
            const int h = col >> 6, d = col & 63;
            *(half8*)&oh[(((size_t)(b * H_ + h) * S_ + s) << 6) + d] = vls;
        } else {
            const int col = n0 + row, m = m0 + cs;
            const int b = m >> 11, s = m & (S_ - 1);
            const int h = col >> 6, d = col & 63;
            *(half8*)&oh[((size_t)(b * H_ + h) * DH_ + d) * S_ + s] = vls;
        }
    }
}

// z=0: Q (scatter, *0.125*log2e for exp2 softmax), z=1: K, z=2: V (transposed)
__global__ __launch_bounds__(256) void gemm_proj(
    const __half* __restrict__ qf, const __half* __restrict__ kf,
    const __half* __restrict__ vf,
    const __half* __restrict__ Wtq, const __half* __restrict__ Wtk,
    const __half* __restrict__ Wtv,
    const float* __restrict__ bq, const float* __restrict__ bk,
    const float* __restrict__ bv,
    __half* __restrict__ qhf, __half* __restrict__ khf, __half* __restrict__ vht)
{
    const __half* As[3] = {qf, kf, vf};
    const __half* Bts[3] = {Wtq, Wtk, Wtv};
    const float* bs[3] = {bq, bk, bv};
    __half* ds[3] = {qhf, khf, vht};
    const int z = blockIdx.z;
    gemm_core(As[z], Bts[z], bs[z], ds[z], z == 2 ? 2 : 0,
              z == 0 ? 0.1803368801111244f : 1.0f);
}

__global__ __launch_bounds__(256) void gemm_final(
    const __half* __restrict__ attf, const __half* __restrict__ Wto,
    const float* __restrict__ bo, float* __restrict__ out)
{
    gemm_core(attf, Wto, bo, out, 1, 1.0f);
}

// ---- flash attention, 32x32 MFMA, T12 in-register P repack ----
// qhf/khf: [B,H,S,64] f16 (Q pre-scaled 0.125*log2e). vht: [B,H,64,S].
// Wave wv: kb=wv>>1 (k-band 32), qb=wv&1 (q-band 32). Per 64-k tile:
// 4 QK MFMA (S^T 32k x 32q) -> 16 exp2 -> 8 cvt_pkrtz + 4 permlane32_swap
// -> 4 PV MFMA into O[2] (64d x 32q, partial over kb). Epilogue: 2-way
// k-band reduce via LDS + lp shfl/LDS reduce.
__global__ __launch_bounds__(256, 4) void attn_f16(
    const __half* __restrict__ qhf, const __half* __restrict__ khf,
    const __half* __restrict__ vht, __half* __restrict__ attf)
{
    __shared__ __align__(16) char smem[36864];

    const int tid = threadIdx.x;
    const int lane = tid & 63, wv = tid >> 6;
    const int l31 = lane & 31, hi = lane >> 5;
    const int kb = wv >> 1, qb = wv & 1;
    const int bh = blockIdx.y;
    const int q0 = blockIdx.x * 64;
    const size_t hbase = (size_t)bh * S_ * DH_;

    // ---- Q B-frags [idx=q=l31][k(d)=hi*8+j] per 16-d slice, from global ----
    half8 qB[4];
    #pragma unroll
    for (int ds = 0; ds < 4; ++ds)
        qB[ds] = *(const half8*)&qhf[hbase
            + (size_t)(q0 + qb * 32 + l31) * DH_ + ds * 16 + hi * 8];

    float lp = 0.f;
    floatx16 O[2];
    #pragma unroll
    for (int i = 0; i < 16; ++i) { O[0][i] = 0.f; O[1][i] = 0.f; }

    // ---- stage tile 0 directly into buf0 ----
    {
        __half (*K0)[72] = (__half(*)[72])smem;
        __half (*V0)[72] = (__half(*)[72])(smem + 9216);
        #pragma unroll
        for (int p = 0; p < 2; ++p) {
            const int c = tid + p * 256;
            const int row = c >> 3, seg = (c & 7) * 8;
            *(half8*)&K0[row][seg] = *(const half8*)&khf[hbase + (size_t)row * DH_ + seg];
            *(half8*)&V0[row][seg] = *(const half8*)&vht[hbase + (size_t)row * S_ + seg];
        }
    }
    // ---- prefetch tile 1 into registers ----
    half8 pk[2], pv[2];
    #pragma unroll
    for (int p = 0; p < 2; ++p) {
        const int c = tid + p * 256;
        const int row = c >> 3, seg = (c & 7) * 8;
        pk[p] = *(const half8*)&khf[hbase + (size_t)(64 + row) * DH_ + seg];
        pv[p] = *(const half8*)&vht[hbase + (size_t)row * S_ + 64 + seg];
    }
    __syncthreads();                       // tile 0 visible

    for (int kt = 0; kt < S_; kt += 64) {
        const int cb = (kt >> 6) & 1;
        __half (*Ks)[72] = (__half(*)[72])(smem + cb * 18432);
        __half (*Vs)[72] = (__half(*)[72])(smem + cb * 18432 + 9216);
        __half (*Kn)[72] = (__half(*)[72])(smem + (cb ^ 1) * 18432);
        __half (*Vn)[72] = (__half(*)[72])(smem + (cb ^ 1) * 18432 + 9216);

        // write tile t+1 into the other buffer (overlaps compute reads)
        if (kt + 64 < S_) {
            #pragma unroll
            for (int p = 0; p < 2; ++p) {
                const int c = tid + p * 256;
                const int row = c >> 3, seg = (c & 7) * 8;
                *(half8*)&Kn[row][seg] = pk[p];
                *(half8*)&Vn[row][seg] = pv[p];
            }
            if (kt + 128 < S_) {           // issue t+2 loads; fly during compute
                #pragma unroll
                for (int p = 0; p < 2; ++p) {
                    const int c = tid + p * 256;
                    const int row = c >> 3, seg = (c & 7) * 8;
                    pk[p] = *(const half8*)&khf[hbase + (size_t)(kt + 128 + row) * DH_ + seg];
                    pv[p] = *(const half8*)&vht[hbase + (size_t)row * S_ + kt + 128 + seg];
                }
            }
        }

        // ---- S^T = K Q^T : 32k (band kb) x 32q (band qb), K-dim = d ----
        floatx16 s;
        #pragma unroll
        for (int i = 0; i < 16; ++i) s[i] = 0.f;
        __builtin_amdgcn_s_setprio(1);
        #pragma unroll
        for (int ds = 0; ds < 4; ++ds) {
            const half8 aK = *(const half8*)&Ks[kb * 32 + l31][ds * 16 + hi * 8];
            s = MFMA3216(aK, qB[ds], s);
        }
        __builtin_amdgcn_s_setprio(0);

        // ---- P^T = exp2(S^T); per-lane partial col sum ----
        #pragma unroll
        for (int r = 0; r < 16; ++r) {
            const float e = __builtin_amdgcn_exp2f(s[r]);
            lp += e;
            s[r] = e;
        }

        // ---- pack to PV B-frags [idx=q][k=hi*8+j] per 16-k slice ----
        half8 pB[2];
        #pragma unroll
        for (int ks = 0; ks < 2; ++ks) {
            int P0 = __builtin_bit_cast(int, __builtin_amdgcn_cvt_pkrtz(s[ks * 8 + 0], s[ks * 8 + 1]));
            int P1 = __builtin_bit_cast(int, __builtin_amdgcn_cvt_pkrtz(s[ks * 8 + 2], s[ks * 8 + 3]));
            int P2 = __builtin_bit_cast(int, __builtin_amdgcn_cvt_pkrtz(s[ks * 8 + 4], s[ks * 8 + 5]));
            int P3 = __builtin_bit_cast(int, __builtin_amdgcn_cvt_pkrtz(s[ks * 8 + 6], s[ks * 8 + 7]));
            half_swap(P0, P2, hi);
            half_swap(P1, P3, hi);
            const intx4 w = {P0, P1, P2, P3};
            pB[ks] = __builtin_bit_cast(half8, w);
        }

        // ---- O^T += V^T P^T over wave's 32-k band ----
        __builtin_amdgcn_s_setprio(1);
        #pragma unroll
        for (int db = 0; db < 2; ++db)
            #pragma unroll
            for (int ks = 0; ks < 2; ++ks) {
                const half8 aV = *(const half8*)&Vs[db * 32 + l31][kb * 32 + ks * 16 + hi * 8];
                O[db] = MFMA3216(aV, pB[ks], O[db]);
            }
        __builtin_amdgcn_s_setprio(0);

        __syncthreads();   // t+1 writes visible; buf reads done before t+2 overwrite
    }

    // ---- epilogue: 2-way k-band reduce + softmax normalize ----
    float (*R)[68] = (float(*)[68])smem;              // [64 d][64 q(+4)]
    __half (*F)[72] = (__half(*)[72])(smem + 17408);  // [64 q][64 d]
    float* Lred = (float*)(smem + 26624);             // [2][64]

    lp += __shfl_xor(lp, 32, 64);                     // combine hi/lo (same q)
    if (lane < 32) Lred[kb * 64 + qb * 32 + l31] = lp;
    if (kb == 1) {
        #pragma unroll
        for (int db = 0; db < 2; ++db)
            #pragma unroll
            for (int r = 0; r < 16; ++r) {
                const int d = db * 32 + (r & 3) + 8 * (r >> 2) + 4 * hi;
                R[d][qb * 32 + l31] = O[db][r];
            }
    }
    __syncthreads();
    if (kb == 0) {
        const int qg = qb * 32 + l31;
        const float il = 1.0f / (Lred[qg] + Lred[64 + qg]);
        #pragma unroll
        for (int db = 0; db < 2; ++db)
            #pragma unroll
            for (int r = 0; r < 16; ++r) {
                const int d = db * 32 + (r & 3) + 8 * (r >> 2) + 4 * hi;
                F[qg][d] = __float2half((O[db][r] + R[d][qg]) * il);
            }
    }
    __syncthreads();

    const int b = bh >> 4, h = bh & 15;
    const int qrow = tid >> 2, dseg = (tid & 3) * 16;
    __half* dstp = &attf[(((size_t)(b * S_ + q0 + qrow)) << 10) + h * DH_ + dseg];
    *(half8*)&dstp[0] = *(const half8*)&F[qrow][dseg];
    *(half8*)&dstp[8] = *(const half8*)&F[qrow][dseg + 8];
}

extern "C" void kernel_launch(void* const* d_in, const int* in_sizes, int n_in,
                              void* d_out, int out_size, void* d_ws, size_t ws_size,
                              hipStream_t stream) {
    const float* q  = (const float*)d_in[0];
    const float* k  = (const float*)d_in[1];
    const float* v  = (const float*)d_in[2];
    const float* Wq = (const float*)d_in[3];
    const float* bq = (const float*)d_in[4];
    const float* Wk = (const float*)d_in[5];
    const float* bk = (const float*)d_in[6];
    const float* Wv = (const float*)d_in[7];
    const float* bv = (const float*)d_in[8];
    const float* Wo = (const float*)d_in[9];
    const float* bo = (const float*)d_in[10];
    float* out = (float*)d_out;

    __half* ws = (__half*)d_ws;
    const size_t NE = (size_t)B_ * S_ * D_;     // 4,194,304
    __half* qf   = ws;
    __half* kf   = ws + NE;
    __half* vf   = ws + 2 * NE;
    __half* qhf  = ws + 3 * NE;
    __half* khf  = ws + 4 * NE;
    __half* vht  = ws + 5 * NE;
    __half* attf = ws + 6 * NE;
    __half* Wtq  = ws + 7 * NE;
    __half* Wtk  = Wtq + (size_t)D_ * D_;
    __half* Wtv  = Wtk + (size_t)D_ * D_;
    __half* Wto  = Wtv + (size_t)D_ * D_;

    const dim3 blk(256);
    prep<<<dim3((unsigned)(NE / 8 / 256), 1, 4), blk, 0, stream>>>(
        q, k, v, qf, kf, vf, Wq, Wk, Wv, Wo, Wtq, Wtk, Wtv, Wto);

    gemm_proj<<<dim3(D_ / 128, (B_ * S_) / 128, 3), blk, 0, stream>>>(
        qf, kf, vf, Wtq, Wtk, Wtv, bq, bk, bv, qhf, khf, vht);

    attn_f16<<<dim3(S_ / 64, B_ * H_), blk, 0, stream>>>(qhf, khf, vht, attf);

    gemm_final<<<dim3(D_ / 128, (B_ * S_) / 128), blk, 0, stream>>>(attf, Wto, bo, out);
}

// Round 6
// 225.063 us; speedup vs baseline: 1.0812x; 1.0203x over previous
//
#include <hip/hip_runtime.h>
#include <hip/hip_fp16.h>
#include <cstddef>

// ---------------------------------------------------------------------------
// CrossAttention, f16 MFMA, round 14.
//   B=2, Sq=Sk=2048, D=1024, H=16, Dh=64
// r13 win (63.8->51.0us attn): 32x32x16 MFMA + cvt_pkrtz/permlane32_swap P
// repack. r14 attacks remaining VALU (41% busy): (1) QBLK=128 / 512-thr
// blocks (8 waves = 2 k-bands x 4 q-bands): staging insts per wave-tile
// halve, same LDS, same per-wave MFMA work; (2) lp row-sum via v_dot2_f32_f16
// on packed P words AFTER PV issue (kills the 16-deep serial f32 add chain
// between exp and pack); (3) pointer-increment prefetch addressing.
// Layouts (32x32x16): A/B [idx=lane&31][k=(lane>>5)*8+j];
//   C/D col=lane&31, row=(reg&3)+8*(reg>>2)+4*(lane>>5)  [m74/m101].
// P repack: P0=pk(s0,s1) P1=pk(s2,s3) P2=pk(s4,s5) P3=pk(s6,s7);
//   swap(P0,P2), swap(P1,P3) -> B-frag words [P0,P1,P2,P3]. (r13-verified)
// ---------------------------------------------------------------------------

#define B_   2
#define S_   2048
#define D_   1024
#define H_   16
#define DH_  64

typedef _Float16 half8 __attribute__((ext_vector_type(8)));
typedef _Float16 half4 __attribute__((ext_vector_type(4)));
typedef _Float16 half2v __attribute__((ext_vector_type(2)));
typedef float floatx4 __attribute__((ext_vector_type(4)));
typedef float floatx16 __attribute__((ext_vector_type(16)));
typedef int intx4 __attribute__((ext_vector_type(4)));

#define MFMA32(a, b, c) __builtin_amdgcn_mfma_f32_16x16x32_f16((a), (b), (c), 0, 0, 0)
#define MFMA3216(a, b, c) __builtin_amdgcn_mfma_f32_32x32x16_f16((a), (b), (c), 0, 0, 0)

#if __has_builtin(__builtin_amdgcn_fdot2)
#define LP_FDOT2 1
#else
#define LP_FDOT2 0
#endif

// exchange: newA = {A.lo32, B.lo32}, newB = {A.hi32, B.hi32}
__device__ __forceinline__ void half_swap(int& a, int& b, const int hi) {
#if __has_builtin(__builtin_amdgcn_permlane32_swap)
    (void)hi;
    auto r = __builtin_amdgcn_permlane32_swap(a, b, false, false);
    a = r[0]; b = r[1];
#else
    const int ax = __shfl_xor(a, 32, 64), bx = __shfl_xor(b, 32, 64);
    const int na = hi ? bx : a;
    b = hi ? b : ax;
    a = na;
#endif
}

// ---- fused: fp32->f16 cvt for q/k/v (z<3) + W transpose x4 (z==3) ----
__global__ __launch_bounds__(256) void prep(
    const float* __restrict__ q, const float* __restrict__ k,
    const float* __restrict__ v,
    __half* __restrict__ qf, __half* __restrict__ kf, __half* __restrict__ vf,
    const float* __restrict__ Wq, const float* __restrict__ Wk,
    const float* __restrict__ Wv, const float* __restrict__ Wo,
    __half* __restrict__ Wtq, __half* __restrict__ Wtk,
    __half* __restrict__ Wtv, __half* __restrict__ Wto)
{
    __shared__ __align__(16) __half T[64][72];
    const int tid = threadIdx.x;
    const int z = blockIdx.z;
    if (z < 3) {
        const float* srcs[3] = {q, k, v};
        __half* dsts[3] = {qf, kf, vf};
        const int i = blockIdx.x * 256 + tid;
        const float4* s = (const float4*)srcs[z];
        const float4 a = s[2 * i], b = s[2 * i + 1];
        half8 h;
        h[0] = (_Float16)a.x; h[1] = (_Float16)a.y; h[2] = (_Float16)a.z; h[3] = (_Float16)a.w;
        h[4] = (_Float16)b.x; h[5] = (_Float16)b.y; h[6] = (_Float16)b.z; h[7] = (_Float16)b.w;
        *(half8*)&dsts[z][(size_t)i * 8] = h;
        return;
    }
    if (blockIdx.x >= 256) return;
    const float* Ws[4] = {Wq, Wk, Wv, Wo};
    __half* Wts[4] = {Wtq, Wtk, Wtv, Wto};
    const int n0 = (blockIdx.x & 15) * 64, k0 = (blockIdx.x >> 4) * 64;
    for (int w = 0; w < 4; ++w) {
        const float* W = Ws[w];
        __half* Wt = Wts[w];
        #pragma unroll
        for (int p = 0; p < 4; ++p) {
            const int c = tid + p * 256;
            const int kr = c >> 4, nc = (c & 15) * 4;
            const float4 a = *(const float4*)&W[(size_t)(k0 + kr) * D_ + n0 + nc];
            T[nc + 0][kr] = __float2half(a.x);
            T[nc + 1][kr] = __float2half(a.y);
            T[nc + 2][kr] = __float2half(a.z);
            T[nc + 3][kr] = __float2half(a.w);
        }
        __syncthreads();
        #pragma unroll
        for (int p = 0; p < 2; ++p) {
            const int c = tid + p * 256;
            const int nr = c >> 3, kc = (c & 7) * 8;
            *(half8*)&Wt[(size_t)(n0 + nr) * D_ + k0 + kc] = *(const half8*)&T[nr][kc];
        }
        __syncthreads();
    }
}

// ---- 128x128 f16 GEMM core, register-prefetch pipelined (r6 proven) ----
// mode 0: dst f16 scatter [B,H,S,Dh] * oscale (coalesced via LDS transpose)
// mode 1: dst fp32 [M][1024] direct
// mode 2: dst f16 transposed [B,H,Dh,S] (coalesced via LDS transpose)
__device__ __forceinline__ void gemm_core(
    const __half* __restrict__ A, const __half* __restrict__ Bt,
    const float* __restrict__ bias, void* __restrict__ dst,
    const int mode, const float oscale)
{
    __shared__ __align__(16) char gsm[36864];
    __half (*As)[72] = (__half(*)[72])gsm;
    __half (*Bs)[72] = (__half(*)[72])(gsm + 18432);

    const int tid = threadIdx.x;
    const int m0 = blockIdx.y * 128, n0 = blockIdx.x * 128;
    const int lane = tid & 63, wv = tid >> 6;
    const int quad = lane >> 4, lr = lane & 15;
    const int wm0 = (wv >> 1) * 64, wn0 = (wv & 1) * 64;

    floatx4 acc[4][4];
    #pragma unroll
    for (int i = 0; i < 4; ++i)
        #pragma unroll
        for (int j = 0; j < 4; ++j)
            acc[i][j] = (floatx4){0.f, 0.f, 0.f, 0.f};

    // prefetch k0 = 0 into registers
    half8 pa[4], pb[4];
    #pragma unroll
    for (int p = 0; p < 4; ++p) {
        const int c = tid + p * 256;
        const int row = c >> 3, seg = (c & 7) * 8;
        pa[p] = *(const half8*)&A [(size_t)(m0 + row) * D_ + seg];
        pb[p] = *(const half8*)&Bt[(size_t)(n0 + row) * D_ + seg];
    }

    for (int k0 = 0; k0 < D_; k0 += 64) {
        __syncthreads();                  // prev iter's LDS reads done
        #pragma unroll
        for (int p = 0; p < 4; ++p) {
            const int c = tid + p * 256;
            const int row = c >> 3, seg = (c & 7) * 8;
            *(half8*)&As[row][seg] = pa[p];
            *(half8*)&Bs[row][seg] = pb[p];
        }
        if (k0 + 64 < D_) {               // issue next tile's loads now;
            #pragma unroll                // they fly during the MFMA section
            for (int p = 0; p < 4; ++p) {
                const int c = tid + p * 256;
                const int row = c >> 3, seg = (c & 7) * 8;
                pa[p] = *(const half8*)&A [(size_t)(m0 + row) * D_ + k0 + 64 + seg];
                pb[p] = *(const half8*)&Bt[(size_t)(n0 + row) * D_ + k0 + 64 + seg];
            }
        }
        __syncthreads();                  // LDS tile visible
        #pragma unroll
        for (int ks = 0; ks < 2; ++ks) {
            const int ko = quad * 8 + ks * 32;
            half8 af[4], bf[4];
            #pragma unroll
            for (int i = 0; i < 4; ++i) af[i] = *(const half8*)&As[wm0 + i * 16 + lr][ko];
            #pragma unroll
            for (int j = 0; j < 4; ++j) bf[j] = *(const half8*)&Bs[wn0 + j * 16 + lr][ko];
            #pragma unroll
            for (int i = 0; i < 4; ++i)
                #pragma unroll
                for (int j = 0; j < 4; ++j)
                    acc[i][j] = MFMA32(af[i], bf[j], acc[i][j]);
        }
    }

    if (mode == 1) {
        float* out = (float*)dst;
        #pragma unroll
        for (int i = 0; i < 4; ++i) {
            #pragma unroll
            for (int j = 0; j < 4; ++j) {
                const int col = n0 + wn0 + j * 16 + lr;
                const float bval = bias[col];
                #pragma unroll
                for (int r = 0; r < 4; ++r) {
                    const int m = m0 + wm0 + i * 16 + quad * 4 + r;
                    out[(size_t)m * D_ + col] = acc[i][j][r] + bval;
                }
            }
        }
        return;
    }

    // ---- LDS transpose epilogue (modes 0 and 2) ----
    __syncthreads();
    __half (*Ct)[136] = (__half(*)[136])gsm;
    #pragma unroll
    for (int i = 0; i < 4; ++i) {
        #pragma unroll
        for (int j = 0; j < 4; ++j) {
            const int nl = wn0 + j * 16 + lr;
            const float bval = bias[n0 + nl];
            #pragma unroll
            for (int r = 0; r < 4; ++r) {
                const int ml = wm0 + i * 16 + quad * 4 + r;
                const _Float16 hv = (_Float16)((acc[i][j][r] + bval) * oscale);
                if (mode == 0) Ct[ml][nl] = hv;
                else           Ct[nl][ml] = hv;
            }
        }
    }
    __syncthreads();
    __half* oh = (__half*)dst;
    #pragma unroll
    for (int p = 0; p < 8; ++p) {
        const int row = (tid >> 4) + p * 16;
        const int cs  = (tid & 15) * 8;
        const half8 vls = *(const half8*)&Ct[row][cs];
        if (mode == 0) {
            const int m = m0 + row, col = n0 + cs;
            const int b = m >> 11, s = m & (S_ - 1);
            const int h = col >> 6, d = col & 63;
            *(half8*)&oh[(((size_t)(b * H_ + h) * S_ + s) << 6) + d] = vls;
        } else {
            const int col = n0 + row, m = m0 + cs;
            const int b = m >> 11, s = m & (S_ - 1);
            const int h = col >> 6, d = col & 63;
            *(half8*)&oh[((size_t)(b * H_ + h) * DH_ + d) * S_ + s] = vls;
        }
    }
}

// z=0: Q (scatter, *0.125*log2e for exp2 softmax), z=1: K, z=2: V (transposed)
__global__ __launch_bounds__(256) void gemm_proj(
    const __half* __restrict__ qf, const __half* __restrict__ kf,
    const __half* __restrict__ vf,
    const __half* __restrict__ Wtq, const __half* __restrict__ Wtk,
    const __half* __restrict__ Wtv,
    const float* __restrict__ bq, const float* __restrict__ bk,
    const float* __restrict__ bv,
    __half* __restrict__ qhf, __half* __restrict__ khf, __half* __restrict__ vht)
{
    const __half* As[3] = {qf, kf, vf};
    const __half* Bts[3] = {Wtq, Wtk, Wtv};
    const float* bs[3] = {bq, bk, bv};
    __half* ds[3] = {qhf, khf, vht};
    const int z = blockIdx.z;
    gemm_core(As[z], Bts[z], bs[z], ds[z], z == 2 ? 2 : 0,
              z == 0 ? 0.1803368801111244f : 1.0f);
}

__global__ __launch_bounds__(256) void gemm_final(
    const __half* __restrict__ attf, const __half* __restrict__ Wto,
    const float* __restrict__ bo, float* __restrict__ out)
{
    gemm_core(attf, Wto, bo, out, 1, 1.0f);
}

// ---- flash attention, 32x32 MFMA, QBLK=128, 512 threads (8 waves) ----
// qhf/khf: [B,H,S,64] f16 (Q pre-scaled 0.125*log2e). vht: [B,H,64,S].
// Wave wv: kb=wv>>2 (k-band 32), qb=wv&3 (q-band 32 of 128). Per 64-k tile
// per wave: 4 QK MFMA -> 16 exp2 -> 8 cvt_pkrtz + 4 permlane32_swap ->
// 4 PV MFMA; lp row-sum via 8 fdot2 on packed P AFTER PV issue (off the
// exp->PV critical path). Staging: 1 K + 1 V half8 per thread per tile
// (half of r13's per-thread work). LDS: double-buffered K/V[64][72] = 36864B.
__global__ __launch_bounds__(512, 4) void attn_f16(
    const __half* __restrict__ qhf, const __half* __restrict__ khf,
    const __half* __restrict__ vht, __half* __restrict__ attf)
{
    __shared__ __align__(16) char smem[36864];

    const int tid = threadIdx.x;
    const int lane = tid & 63, wv = tid >> 6;
    const int l31 = lane & 31, hi = lane >> 5;
    const int kb = wv >> 2, qb = wv & 3;
    const int bh = blockIdx.y;
    const int q0 = blockIdx.x * 128;
    const size_t hbase = (size_t)bh * S_ * DH_;

    // ---- Q B-frags [idx=q=l31][k(d)=hi*8+j] per 16-d slice, from global ----
    half8 qB[4];
    #pragma unroll
    for (int ds = 0; ds < 4; ++ds)
        qB[ds] = *(const half8*)&qhf[hbase
            + (size_t)(q0 + qb * 32 + l31) * DH_ + ds * 16 + hi * 8];

    float lp0 = 0.f, lp1 = 0.f;
#if !LP_FDOT2
    float lp2 = 0.f, lp3 = 0.f;
#endif
    floatx16 O[2];
    #pragma unroll
    for (int i = 0; i < 16; ++i) { O[0][i] = 0.f; O[1][i] = 0.f; }

    // ---- staging mapping (512 thr): one K + one V half8 per thread ----
    const int srow = tid >> 3, sseg = (tid & 7) * 8;
    const __half* kg = khf + hbase + (size_t)srow * DH_ + sseg;  // += 64*DH_/tile
    const __half* vg = vht + hbase + (size_t)srow * S_ + sseg;   // += 64/tile

    // ---- stage tile 0 directly into buf0 ----
    {
        __half (*K0)[72] = (__half(*)[72])smem;
        __half (*V0)[72] = (__half(*)[72])(smem + 9216);
        *(half8*)&K0[srow][sseg] = *(const half8*)kg;
        *(half8*)&V0[srow][sseg] = *(const half8*)vg;
    }
    // ---- prefetch tile 1 into registers ----
    kg += 64 * DH_; vg += 64;
    half8 pk = *(const half8*)kg;
    half8 pv = *(const half8*)vg;
    __syncthreads();                       // tile 0 visible

    const half2v one2 = {(_Float16)1.0f, (_Float16)1.0f};

    for (int kt = 0; kt < S_; kt += 64) {
        const int cb = (kt >> 6) & 1;
        __half (*Ks)[72] = (__half(*)[72])(smem + cb * 18432);
        __half (*Vs)[72] = (__half(*)[72])(smem + cb * 18432 + 9216);
        __half (*Kn)[72] = (__half(*)[72])(smem + (cb ^ 1) * 18432);
        __half (*Vn)[72] = (__half(*)[72])(smem + (cb ^ 1) * 18432 + 9216);

        // write tile t+1 into the other buffer (overlaps compute reads)
        if (kt + 64 < S_) {
            *(half8*)&Kn[srow][sseg] = pk;
            *(half8*)&Vn[srow][sseg] = pv;
            if (kt + 128 < S_) {           // issue t+2 loads; fly during compute
                kg += 64 * DH_; vg += 64;
                pk = *(const half8*)kg;
                pv = *(const half8*)vg;
            }
        }

        // ---- S^T = K Q^T : 32k (band kb) x 32q (band qb), K-dim = d ----
        floatx16 s;
        #pragma unroll
        for (int i = 0; i < 16; ++i) s[i] = 0.f;
        __builtin_amdgcn_s_setprio(1);
        #pragma unroll
        for (int ds = 0; ds < 4; ++ds) {
            const half8 aK = *(const half8*)&Ks[kb * 32 + l31][ds * 16 + hi * 8];
            s = MFMA3216(aK, qB[ds], s);
        }
        __builtin_amdgcn_s_setprio(0);

        // ---- P^T = exp2(S^T) ----
        #pragma unroll
        for (int r = 0; r < 16; ++r) {
            const float e = __builtin_amdgcn_exp2f(s[r]);
#if !LP_FDOT2
            (r & 2) ? ((r & 1) ? (lp3 += e) : (lp2 += e))
                    : ((r & 1) ? (lp1 += e) : (lp0 += e));
#endif
            s[r] = e;
        }

        // ---- pack to PV B-frags [idx=q][k=hi*8+j] per 16-k slice ----
        half8 pB[2];
        int PW[2][4];
        #pragma unroll
        for (int ks = 0; ks < 2; ++ks) {
            int P0 = __builtin_bit_cast(int, __builtin_amdgcn_cvt_pkrtz(s[ks * 8 + 0], s[ks * 8 + 1]));
            int P1 = __builtin_bit_cast(int, __builtin_amdgcn_cvt_pkrtz(s[ks * 8 + 2], s[ks * 8 + 3]));
            int P2 = __builtin_bit_cast(int, __builtin_amdgcn_cvt_pkrtz(s[ks * 8 + 4], s[ks * 8 + 5]));
            int P3 = __builtin_bit_cast(int, __builtin_amdgcn_cvt_pkrtz(s[ks * 8 + 6], s[ks * 8 + 7]));
            half_swap(P0, P2, hi);
            half_swap(P1, P3, hi);
            PW[ks][0] = P0; PW[ks][1] = P1; PW[ks][2] = P2; PW[ks][3] = P3;
            const intx4 w = {P0, P1, P2, P3};
            pB[ks] = __builtin_bit_cast(half8, w);
        }

        // ---- O^T += V^T P^T over wave's 32-k band ----
        __builtin_amdgcn_s_setprio(1);
        #pragma unroll
        for (int db = 0; db < 2; ++db)
            #pragma unroll
            for (int ks = 0; ks < 2; ++ks) {
                const half8 aV = *(const half8*)&Vs[db * 32 + l31][kb * 32 + ks * 16 + hi * 8];
                O[db] = MFMA3216(aV, pB[ks], O[db]);
            }
        __builtin_amdgcn_s_setprio(0);

#if LP_FDOT2
        // ---- lp row-sum from packed P (VALU-free window: MFMA pipe busy) ----
        #pragma unroll
        for (int ks = 0; ks < 2; ++ks) {
            lp0 = __builtin_amdgcn_fdot2(__builtin_bit_cast(half2v, PW[ks][0]), one2, lp0, false);
            lp1 = __builtin_amdgcn_fdot2(__builtin_bit_cast(half2v, PW[ks][1]), one2, lp1, false);
            lp0 = __builtin_amdgcn_fdot2(__builtin_bit_cast(half2v, PW[ks][2]), one2, lp0, false);
            lp1 = __builtin_amdgcn_fdot2(__builtin_bit_cast(half2v, PW[ks][3]), one2, lp1, false);
        }
#endif

        __syncthreads();   // t+1 writes visible; buf reads done before t+2 overwrite
    }

    // ---- epilogue: 2-way k-band reduce + softmax normalize, 128 q rows ----
    float (*R)[132] = (float(*)[132])smem;            // [64 d][128 q(+4)] f32
    float* Lred = (float*)(smem + 33792);             // [2][128] f32

#if LP_FDOT2
    float lp = lp0 + lp1;
#else
    float lp = (lp0 + lp1) + (lp2 + lp3);
#endif
    lp += __shfl_xor(lp, 32, 64);                     // combine hi/lo (same q)
    const int qg = qb * 32 + l31;
    if (lane < 32) Lred[kb * 128 + qg] = lp;
    if (kb == 1) {
        #pragma unroll
        for (int db = 0; db < 2; ++db)
            #pragma unroll
            for (int r = 0; r < 16; ++r) {
                const int d = db * 32 + (r & 3) + 8 * (r >> 2) + 4 * hi;
                R[d][qg] = O[db][r];
            }
    }
    __syncthreads();
    if (kb == 0) {
        const float il = 1.0f / (Lred[qg] + Lred[128 + qg]);
        #pragma unroll
        for (int db = 0; db < 2; ++db)
            #pragma unroll
            for (int r = 0; r < 16; ++r) {
                const int d = db * 32 + (r & 3) + 8 * (r >> 2) + 4 * hi;
                O[db][r] = (O[db][r] + R[d][qg]) * il;
            }
    }
    __syncthreads();
    __half (*F)[72] = (__half(*)[72])smem;            // [128 q][64 d] f16
    if (kb == 0) {
        #pragma unroll
        for (int db = 0; db < 2; ++db)
            #pragma unroll
            for (int t = 0; t < 4; ++t) {
                half4 hv;
                #pragma unroll
                for (int r = 0; r < 4; ++r) hv[r] = (_Float16)O[db][t * 4 + r];
                *(half4*)&F[qg][db * 32 + t * 8 + hi * 4] = hv;
            }
    }
    __syncthreads();

    const int b = bh >> 4, h = bh & 15;
    const int qrow = tid >> 2, dseg = (tid & 3) * 16;
    __half* dstp = &attf[(((size_t)(b * S_ + q0 + qrow)) << 10) + h * DH_ + dseg];
    *(half8*)&dstp[0] = *(const half8*)&F[qrow][dseg];
    *(half8*)&dstp[8] = *(const half8*)&F[qrow][dseg + 8];
}

extern "C" void kernel_launch(void* const* d_in, const int* in_sizes, int n_in,
                              void* d_out, int out_size, void* d_ws, size_t ws_size,
                              hipStream_t stream) {
    const float* q  = (const float*)d_in[0];
    const float* k  = (const float*)d_in[1];
    const float* v  = (const float*)d_in[2];
    const float* Wq = (const float*)d_in[3];
    const float* bq = (const float*)d_in[4];
    const float* Wk = (const float*)d_in[5];
    const float* bk = (const float*)d_in[6];
    const float* Wv = (const float*)d_in[7];
    const float* bv = (const float*)d_in[8];
    const float* Wo = (const float*)d_in[9];
    const float* bo = (const float*)d_in[10];
    float* out = (float*)d_out;

    __half* ws = (__half*)d_ws;
    const size_t NE = (size_t)B_ * S_ * D_;     // 4,194,304
    __half* qf   = ws;
    __half* kf   = ws + NE;
    __half* vf   = ws + 2 * NE;
    __half* qhf  = ws + 3 * NE;
    __half* khf  = ws + 4 * NE;
    __half* vht  = ws + 5 * NE;
    __half* attf = ws + 6 * NE;
    __half* Wtq  = ws + 7 * NE;
    __half* Wtk  = Wtq + (size_t)D_ * D_;
    __half* Wtv  = Wtk + (size_t)D_ * D_;
    __half* Wto  = Wtv + (size_t)D_ * D_;

    const dim3 blk(256);
    prep<<<dim3((unsigned)(NE / 8 / 256), 1, 4), blk, 0, stream>>>(
        q, k, v, qf, kf, vf, Wq, Wk, Wv, Wo, Wtq, Wtk, Wtv, Wto);

    gemm_proj<<<dim3(D_ / 128, (B_ * S_) / 128, 3), blk, 0, stream>>>(
        qf, kf, vf, Wtq, Wtk, Wtv, bq, bk, bv, qhf, khf, vht);

    attn_f16<<<dim3(S_ / 128, B_ * H_), dim3(512), 0, stream>>>(qhf, khf, vht, attf);

    gemm_final<<<dim3(D_ / 128, (B_ * S_) / 128), blk, 0, stream>>>(attf, Wto, bo, out);
}

// Round 7
// 222.708 us; speedup vs baseline: 1.0927x; 1.0106x over previous
//
#include <hip/hip_runtime.h>
#include <hip/hip_fp16.h>
#include <cstddef>

// ---------------------------------------------------------------------------
// CrossAttention, f16 MFMA, round 15.
//   B=2, Sq=Sk=2048, D=1024, H=16, Dh=64
// r14: attn fixed (32x32 MFMA + permlane repack + QBLK=128 + fdot2 lp);
// profile flipped: gemm_proj now #1 (49us, MfmaUtil 19, FETCH 101MB vs ~35
// ideal -> XCD-scattered A-panels; 2 barriers/K-step). r15:
//   (a) bijective XCD swizzle (T1) on gemm_proj/gemm_final/attn grids
//       (all %8==0): each XCD gets contiguous tile range -> A-panels /
//       per-head K/V fetched once per XCD.
//   (b) gemm_core: single-barrier double-buffered K-loop (r12 pattern),
//       dynamic LDS 73728B, setprio around MFMA.
// Layouts (32x32x16): A/B [idx=lane&31][k=(lane>>5)*8+j];
//   C/D col=lane&31, row=(reg&3)+8*(reg>>2)+4*(lane>>5)  [m74/m101].
// P repack: P0=pk(s0,s1) P1=pk(s2,s3) P2=pk(s4,s5) P3=pk(s6,s7);
//   swap(P0,P2), swap(P1,P3) -> B-frag words [P0,P1,P2,P3]. (r13-verified)
// ---------------------------------------------------------------------------

#define B_   2
#define S_   2048
#define D_   1024
#define H_   16
#define DH_  64

typedef _Float16 half8 __attribute__((ext_vector_type(8)));
typedef _Float16 half4 __attribute__((ext_vector_type(4)));
typedef _Float16 half2v __attribute__((ext_vector_type(2)));
typedef float floatx4 __attribute__((ext_vector_type(4)));
typedef float floatx16 __attribute__((ext_vector_type(16)));
typedef int intx4 __attribute__((ext_vector_type(4)));

#define MFMA32(a, b, c) __builtin_amdgcn_mfma_f32_16x16x32_f16((a), (b), (c), 0, 0, 0)
#define MFMA3216(a, b, c) __builtin_amdgcn_mfma_f32_32x32x16_f16((a), (b), (c), 0, 0, 0)

#if __has_builtin(__builtin_amdgcn_fdot2)
#define LP_FDOT2 1
#else
#define LP_FDOT2 0
#endif

// exchange: newA = {A.lo32, B.lo32}, newB = {A.hi32, B.hi32}
__device__ __forceinline__ void half_swap(int& a, int& b, const int hi) {
#if __has_builtin(__builtin_amdgcn_permlane32_swap)
    (void)hi;
    auto r = __builtin_amdgcn_permlane32_swap(a, b, false, false);
    a = r[0]; b = r[1];
#else
    const int ax = __shfl_xor(a, 32, 64), bx = __shfl_xor(b, 32, 64);
    const int na = hi ? bx : a;
    b = hi ? b : ax;
    a = na;
#endif
}

// ---- fused: fp32->f16 cvt for q/k/v (z<3) + W transpose x4 (z==3) ----
__global__ __launch_bounds__(256) void prep(
    const float* __restrict__ q, const float* __restrict__ k,
    const float* __restrict__ v,
    __half* __restrict__ qf, __half* __restrict__ kf, __half* __restrict__ vf,
    const float* __restrict__ Wq, const float* __restrict__ Wk,
    const float* __restrict__ Wv, const float* __restrict__ Wo,
    __half* __restrict__ Wtq, __half* __restrict__ Wtk,
    __half* __restrict__ Wtv, __half* __restrict__ Wto)
{
    __shared__ __align__(16) __half T[64][72];
    const int tid = threadIdx.x;
    const int z = blockIdx.z;
    if (z < 3) {
        const float* srcs[3] = {q, k, v};
        __half* dsts[3] = {qf, kf, vf};
        const int i = blockIdx.x * 256 + tid;
        const float4* s = (const float4*)srcs[z];
        const float4 a = s[2 * i], b = s[2 * i + 1];
        half8 h;
        h[0] = (_Float16)a.x; h[1] = (_Float16)a.y; h[2] = (_Float16)a.z; h[3] = (_Float16)a.w;
        h[4] = (_Float16)b.x; h[5] = (_Float16)b.y; h[6] = (_Float16)b.z; h[7] = (_Float16)b.w;
        *(half8*)&dsts[z][(size_t)i * 8] = h;
        return;
    }
    if (blockIdx.x >= 256) return;
    const float* Ws[4] = {Wq, Wk, Wv, Wo};
    __half* Wts[4] = {Wtq, Wtk, Wtv, Wto};
    const int n0 = (blockIdx.x & 15) * 64, k0 = (blockIdx.x >> 4) * 64;
    for (int w = 0; w < 4; ++w) {
        const float* W = Ws[w];
        __half* Wt = Wts[w];
        #pragma unroll
        for (int p = 0; p < 4; ++p) {
            const int c = tid + p * 256;
            const int kr = c >> 4, nc = (c & 15) * 4;
            const float4 a = *(const float4*)&W[(size_t)(k0 + kr) * D_ + n0 + nc];
            T[nc + 0][kr] = __float2half(a.x);
            T[nc + 1][kr] = __float2half(a.y);
            T[nc + 2][kr] = __float2half(a.z);
            T[nc + 3][kr] = __float2half(a.w);
        }
        __syncthreads();
        #pragma unroll
        for (int p = 0; p < 2; ++p) {
            const int c = tid + p * 256;
            const int nr = c >> 3, kc = (c & 7) * 8;
            *(half8*)&Wt[(size_t)(n0 + nr) * D_ + k0 + kc] = *(const half8*)&T[nr][kc];
        }
        __syncthreads();
    }
}

// ---- 128x128 f16 GEMM core, single-barrier LDS double-buffer (r15) ----
// Dynamic LDS: 2 x (As[128][72] + Bs[128][72]) = 73728 B.
// mode 0: dst f16 scatter [B,H,S,Dh] * oscale (coalesced via LDS transpose)
// mode 1: dst fp32 [M][1024] direct
// mode 2: dst f16 transposed [B,H,Dh,S] (coalesced via LDS transpose)
__device__ __forceinline__ void gemm_core(
    const __half* __restrict__ A, const __half* __restrict__ Bt,
    const float* __restrict__ bias, void* __restrict__ dst,
    const int mode, const float oscale, const int m0, const int n0)
{
    extern __shared__ __align__(16) char gsm[];

    const int tid = threadIdx.x;
    const int lane = tid & 63, wv = tid >> 6;
    const int quad = lane >> 4, lr = lane & 15;
    const int wm0 = (wv >> 1) * 64, wn0 = (wv & 1) * 64;

    floatx4 acc[4][4];
    #pragma unroll
    for (int i = 0; i < 4; ++i)
        #pragma unroll
        for (int j = 0; j < 4; ++j)
            acc[i][j] = (floatx4){0.f, 0.f, 0.f, 0.f};

    const int srow = tid >> 3, sseg = (tid & 7) * 8;

    // ---- stage tile 0 into buf0; prefetch tile 1 into registers ----
    half8 pa[4], pb[4];
    #pragma unroll
    for (int p = 0; p < 4; ++p) {
        const int c = tid + p * 256;
        const int row = c >> 3, seg = (c & 7) * 8;
        pa[p] = *(const half8*)&A [(size_t)(m0 + row) * D_ + seg];
        pb[p] = *(const half8*)&Bt[(size_t)(n0 + row) * D_ + seg];
    }
    {
        __half (*As0)[72] = (__half(*)[72])gsm;
        __half (*Bs0)[72] = (__half(*)[72])(gsm + 18432);
        #pragma unroll
        for (int p = 0; p < 4; ++p) {
            const int c = tid + p * 256;
            const int row = c >> 3, seg = (c & 7) * 8;
            *(half8*)&As0[row][seg] = pa[p];
            *(half8*)&Bs0[row][seg] = pb[p];
        }
    }
    #pragma unroll
    for (int p = 0; p < 4; ++p) {
        const int c = tid + p * 256;
        const int row = c >> 3, seg = (c & 7) * 8;
        pa[p] = *(const half8*)&A [(size_t)(m0 + row) * D_ + 64 + seg];
        pb[p] = *(const half8*)&Bt[(size_t)(n0 + row) * D_ + 64 + seg];
    }
    __syncthreads();                      // tile 0 visible

    for (int k0 = 0; k0 < D_; k0 += 64) {
        const int cb = (k0 >> 6) & 1;
        __half (*As)[72] = (__half(*)[72])(gsm + cb * 36864);
        __half (*Bs)[72] = (__half(*)[72])(gsm + cb * 36864 + 18432);
        __half (*An)[72] = (__half(*)[72])(gsm + (cb ^ 1) * 36864);
        __half (*Bn)[72] = (__half(*)[72])(gsm + (cb ^ 1) * 36864 + 18432);

        // write tile t+1 into other buffer (overlaps compute reads of cur)
        if (k0 + 64 < D_) {
            #pragma unroll
            for (int p = 0; p < 4; ++p) {
                const int c = tid + p * 256;
                const int row = c >> 3, seg = (c & 7) * 8;
                *(half8*)&An[row][seg] = pa[p];
                *(half8*)&Bn[row][seg] = pb[p];
            }
            if (k0 + 128 < D_) {          // issue t+2 loads; fly during MFMA
                #pragma unroll
                for (int p = 0; p < 4; ++p) {
                    const int c = tid + p * 256;
                    const int row = c >> 3, seg = (c & 7) * 8;
                    pa[p] = *(const half8*)&A [(size_t)(m0 + row) * D_ + k0 + 128 + seg];
                    pb[p] = *(const half8*)&Bt[(size_t)(n0 + row) * D_ + k0 + 128 + seg];
                }
            }
        }

        __builtin_amdgcn_s_setprio(1);
        #pragma unroll
        for (int ks = 0; ks < 2; ++ks) {
            const int ko = quad * 8 + ks * 32;
            half8 af[4], bf[4];
            #pragma unroll
            for (int i = 0; i < 4; ++i) af[i] = *(const half8*)&As[wm0 + i * 16 + lr][ko];
            #pragma unroll
            for (int j = 0; j < 4; ++j) bf[j] = *(const half8*)&Bs[wn0 + j * 16 + lr][ko];
            #pragma unroll
            for (int i = 0; i < 4; ++i)
                #pragma unroll
                for (int j = 0; j < 4; ++j)
                    acc[i][j] = MFMA32(af[i], bf[j], acc[i][j]);
        }
        __builtin_amdgcn_s_setprio(0);

        __syncthreads();   // t+1 writes visible; cur reads done before overwrite
    }

    if (mode == 1) {
        float* out = (float*)dst;
        #pragma unroll
        for (int i = 0; i < 4; ++i) {
            #pragma unroll
            for (int j = 0; j < 4; ++j) {
                const int col = n0 + wn0 + j * 16 + lr;
                const float bval = bias[col];
                #pragma unroll
                for (int r = 0; r < 4; ++r) {
                    const int m = m0 + wm0 + i * 16 + quad * 4 + r;
                    out[(size_t)m * D_ + col] = acc[i][j][r] + bval;
                }
            }
        }
        return;
    }

    // ---- LDS transpose epilogue (modes 0 and 2); loop ended with barrier ----
    __half (*Ct)[136] = (__half(*)[136])gsm;
    #pragma unroll
    for (int i = 0; i < 4; ++i) {
        #pragma unroll
        for (int j = 0; j < 4; ++j) {
            const int nl = wn0 + j * 16 + lr;
            const float bval = bias[n0 + nl];
            #pragma unroll
            for (int r = 0; r < 4; ++r) {
                const int ml = wm0 + i * 16 + quad * 4 + r;
                const _Float16 hv = (_Float16)((acc[i][j][r] + bval) * oscale);
                if (mode == 0) Ct[ml][nl] = hv;
                else           Ct[nl][ml] = hv;
            }
        }
    }
    __syncthreads();
    __half* oh = (__half*)dst;
    #pragma unroll
    for (int p = 0; p < 8; ++p) {
        const int row = (tid >> 4) + p * 16;
        const int cs  = (tid & 15) * 8;
        const half8 vls = *(const half8*)&Ct[row][cs];
        if (mode == 0) {
            const int m = m0 + row, col = n0 + cs;
            const int b = m >> 11, s = m & (S_ - 1);
            const int h = col >> 6, d = col & 63;
            *(half8*)&oh[(((size_t)(b * H_ + h) * S_ + s) << 6) + d] = vls;
        } else {
            const int col = n0 + row, m = m0 + cs;
            const int b = m >> 11, s = m & (S_ - 1);
            const int h = col >> 6, d = col & 63;
            *(half8*)&oh[((size_t)(b * H_ + h) * DH_ + d) * S_ + s] = vls;
        }
    }
}

// z=0: Q (scatter, *0.125*log2e for exp2 softmax), z=1: K, z=2: V (transposed)
// XCD swizzle: grid (8,32,3)=768 blocks, 96/XCD contiguous (bijective).
__global__ __launch_bounds__(256) void gemm_proj(
    const __half* __restrict__ qf, const __half* __restrict__ kf,
    const __half* __restrict__ vf,
    const __half* __restrict__ Wtq, const __half* __restrict__ Wtk,
    const __half* __restrict__ Wtv,
    const float* __restrict__ bq, const float* __restrict__ bk,
    const float* __restrict__ bv,
    __half* __restrict__ qhf, __half* __restrict__ khf, __half* __restrict__ vht)
{
    const int flat = blockIdx.x + (blockIdx.y << 3) + (blockIdx.z << 8);
    const int wid = (flat & 7) * 96 + (flat >> 3);
    const int z = wid >> 8;
    const int rem = wid & 255;
    const int m0 = (rem >> 3) * 128, n0 = (rem & 7) * 128;

    const __half* As[3] = {qf, kf, vf};
    const __half* Bts[3] = {Wtq, Wtk, Wtv};
    const float* bs[3] = {bq, bk, bv};
    __half* ds[3] = {qhf, khf, vht};
    gemm_core(As[z], Bts[z], bs[z], ds[z], z == 2 ? 2 : 0,
              z == 0 ? 0.1803368801111244f : 1.0f, m0, n0);
}

// XCD swizzle: grid (8,32)=256 blocks, 32/XCD contiguous.
__global__ __launch_bounds__(256) void gemm_final(
    const __half* __restrict__ attf, const __half* __restrict__ Wto,
    const float* __restrict__ bo, float* __restrict__ out)
{
    const int flat = blockIdx.x + (blockIdx.y << 3);
    const int wid = (flat & 7) * 32 + (flat >> 3);
    const int m0 = (wid >> 3) * 128, n0 = (wid & 7) * 128;
    gemm_core(attf, Wto, bo, out, 1, 1.0f, m0, n0);
}

// ---- flash attention, 32x32 MFMA, QBLK=128, 512 threads (8 waves) ----
// qhf/khf: [B,H,S,64] f16 (Q pre-scaled 0.125*log2e). vht: [B,H,64,S].
// Wave wv: kb=wv>>2 (k-band 32), qb=wv&3 (q-band 32 of 128). Per 64-k tile
// per wave: 4 QK MFMA -> 16 exp2 -> 8 cvt_pkrtz + 4 permlane32_swap ->
// 4 PV MFMA; lp row-sum via 8 fdot2 on packed P AFTER PV issue.
// XCD swizzle: grid (16,32)=512 blocks, 64/XCD = 4 complete heads' K/V.
__global__ __launch_bounds__(512, 4) void attn_f16(
    const __half* __restrict__ qhf, const __half* __restrict__ khf,
    const __half* __restrict__ vht, __half* __restrict__ attf)
{
    __shared__ __align__(16) char smem[36864];

    const int tid = threadIdx.x;
    const int lane = tid & 63, wv = tid >> 6;
    const int l31 = lane & 31, hi = lane >> 5;
    const int kb = wv >> 2, qb = wv & 3;
    const int flat = blockIdx.x + (blockIdx.y << 4);
    const int wid = ((flat & 7) << 6) + (flat >> 3);
    const int bh = wid >> 4;
    const int q0 = (wid & 15) * 128;
    const size_t hbase = (size_t)bh * S_ * DH_;

    // ---- Q B-frags [idx=q=l31][k(d)=hi*8+j] per 16-d slice, from global ----
    half8 qB[4];
    #pragma unroll
    for (int ds = 0; ds < 4; ++ds)
        qB[ds] = *(const half8*)&qhf[hbase
            + (size_t)(q0 + qb * 32 + l31) * DH_ + ds * 16 + hi * 8];

    float lp0 = 0.f, lp1 = 0.f;
#if !LP_FDOT2
    float lp2 = 0.f, lp3 = 0.f;
#endif
    floatx16 O[2];
    #pragma unroll
    for (int i = 0; i < 16; ++i) { O[0][i] = 0.f; O[1][i] = 0.f; }

    // ---- staging mapping (512 thr): one K + one V half8 per thread ----
    const int srow = tid >> 3, sseg = (tid & 7) * 8;
    const __half* kg = khf + hbase + (size_t)srow * DH_ + sseg;  // += 64*DH_/tile
    const __half* vg = vht + hbase + (size_t)srow * S_ + sseg;   // += 64/tile

    // ---- stage tile 0 directly into buf0 ----
    {
        __half (*K0)[72] = (__half(*)[72])smem;
        __half (*V0)[72] = (__half(*)[72])(smem + 9216);
        *(half8*)&K0[srow][sseg] = *(const half8*)kg;
        *(half8*)&V0[srow][sseg] = *(const half8*)vg;
    }
    // ---- prefetch tile 1 into registers ----
    kg += 64 * DH_; vg += 64;
    half8 pk = *(const half8*)kg;
    half8 pv = *(const half8*)vg;
    __syncthreads();                       // tile 0 visible

    const half2v one2 = {(_Float16)1.0f, (_Float16)1.0f};

    for (int kt = 0; kt < S_; kt += 64) {
        const int cb = (kt >> 6) & 1;
        __half (*Ks)[72] = (__half(*)[72])(smem + cb * 18432);
        __half (*Vs)[72] = (__half(*)[72])(smem + cb * 18432 + 9216);
        __half (*Kn)[72] = (__half(*)[72])(smem + (cb ^ 1) * 18432);
        __half (*Vn)[72] = (__half(*)[72])(smem + (cb ^ 1) * 18432 + 9216);

        // write tile t+1 into the other buffer (overlaps compute reads)
        if (kt + 64 < S_) {
            *(half8*)&Kn[srow][sseg] = pk;
            *(half8*)&Vn[srow][sseg] = pv;
            if (kt + 128 < S_) {           // issue t+2 loads; fly during compute
                kg += 64 * DH_; vg += 64;
                pk = *(const half8*)kg;
                pv = *(const half8*)vg;
            }
        }

        // ---- S^T = K Q^T : 32k (band kb) x 32q (band qb), K-dim = d ----
        floatx16 s;
        #pragma unroll
        for (int i = 0; i < 16; ++i) s[i] = 0.f;
        __builtin_amdgcn_s_setprio(1);
        #pragma unroll
        for (int ds = 0; ds < 4; ++ds) {
            const half8 aK = *(const half8*)&Ks[kb * 32 + l31][ds * 16 + hi * 8];
            s = MFMA3216(aK, qB[ds], s);
        }
        __builtin_amdgcn_s_setprio(0);

        // ---- P^T = exp2(S^T) ----
        #pragma unroll
        for (int r = 0; r < 16; ++r) {
            const float e = __builtin_amdgcn_exp2f(s[r]);
#if !LP_FDOT2
            (r & 2) ? ((r & 1) ? (lp3 += e) : (lp2 += e))
                    : ((r & 1) ? (lp1 += e) : (lp0 += e));
#endif
            s[r] = e;
        }

        // ---- pack to PV B-frags [idx=q][k=hi*8+j] per 16-k slice ----
        half8 pB[2];
        int PW[2][4];
        #pragma unroll
        for (int ks = 0; ks < 2; ++ks) {
            int P0 = __builtin_bit_cast(int, __builtin_amdgcn_cvt_pkrtz(s[ks * 8 + 0], s[ks * 8 + 1]));
            int P1 = __builtin_bit_cast(int, __builtin_amdgcn_cvt_pkrtz(s[ks * 8 + 2], s[ks * 8 + 3]));
            int P2 = __builtin_bit_cast(int, __builtin_amdgcn_cvt_pkrtz(s[ks * 8 + 4], s[ks * 8 + 5]));
            int P3 = __builtin_bit_cast(int, __builtin_amdgcn_cvt_pkrtz(s[ks * 8 + 6], s[ks * 8 + 7]));
            half_swap(P0, P2, hi);
            half_swap(P1, P3, hi);
            PW[ks][0] = P0; PW[ks][1] = P1; PW[ks][2] = P2; PW[ks][3] = P3;
            const intx4 w = {P0, P1, P2, P3};
            pB[ks] = __builtin_bit_cast(half8, w);
        }

        // ---- O^T += V^T P^T over wave's 32-k band ----
        __builtin_amdgcn_s_setprio(1);
        #pragma unroll
        for (int db = 0; db < 2; ++db)
            #pragma unroll
            for (int ks = 0; ks < 2; ++ks) {
                const half8 aV = *(const half8*)&Vs[db * 32 + l31][kb * 32 + ks * 16 + hi * 8];
                O[db] = MFMA3216(aV, pB[ks], O[db]);
            }
        __builtin_amdgcn_s_setprio(0);

#if LP_FDOT2
        // ---- lp row-sum from packed P (VALU-free window: MFMA pipe busy) ----
        #pragma unroll
        for (int ks = 0; ks < 2; ++ks) {
            lp0 = __builtin_amdgcn_fdot2(__builtin_bit_cast(half2v, PW[ks][0]), one2, lp0, false);
            lp1 = __builtin_amdgcn_fdot2(__builtin_bit_cast(half2v, PW[ks][1]), one2, lp1, false);
            lp0 = __builtin_amdgcn_fdot2(__builtin_bit_cast(half2v, PW[ks][2]), one2, lp0, false);
            lp1 = __builtin_amdgcn_fdot2(__builtin_bit_cast(half2v, PW[ks][3]), one2, lp1, false);
        }
#endif

        __syncthreads();   // t+1 writes visible; buf reads done before t+2 overwrite
    }

    // ---- epilogue: 2-way k-band reduce + softmax normalize, 128 q rows ----
    float (*R)[132] = (float(*)[132])smem;            // [64 d][128 q(+4)] f32
    float* Lred = (float*)(smem + 33792);             // [2][128] f32

#if LP_FDOT2
    float lp = lp0 + lp1;
#else
    float lp = (lp0 + lp1) + (lp2 + lp3);
#endif
    lp += __shfl_xor(lp, 32, 64);                     // combine hi/lo (same q)
    const int qg = qb * 32 + l31;
    if (lane < 32) Lred[kb * 128 + qg] = lp;
    if (kb == 1) {
        #pragma unroll
        for (int db = 0; db < 2; ++db)
            #pragma unroll
            for (int r = 0; r < 16; ++r) {
                const int d = db * 32 + (r & 3) + 8 * (r >> 2) + 4 * hi;
                R[d][qg] = O[db][r];
            }
    }
    __syncthreads();
    if (kb == 0) {
        const float il = 1.0f / (Lred[qg] + Lred[128 + qg]);
        #pragma unroll
        for (int db = 0; db < 2; ++db)
            #pragma unroll
            for (int r = 0; r < 16; ++r) {
                const int d = db * 32 + (r & 3) + 8 * (r >> 2) + 4 * hi;
                O[db][r] = (O[db][r] + R[d][qg]) * il;
            }
    }
    __syncthreads();
    __half (*F)[72] = (__half(*)[72])smem;            // [128 q][64 d] f16
    if (kb == 0) {
        #pragma unroll
        for (int db = 0; db < 2; ++db)
            #pragma unroll
            for (int t = 0; t < 4; ++t) {
                half4 hv;
                #pragma unroll
                for (int r = 0; r < 4; ++r) hv[r] = (_Float16)O[db][t * 4 + r];
                *(half4*)&F[qg][db * 32 + t * 8 + hi * 4] = hv;
            }
    }
    __syncthreads();

    const int b = bh >> 4, h = bh & 15;
    const int qrow = tid >> 2, dseg = (tid & 3) * 16;
    __half* dstp = &attf[(((size_t)(b * S_ + q0 + qrow)) << 10) + h * DH_ + dseg];
    *(half8*)&dstp[0] = *(const half8*)&F[qrow][dseg];
    *(half8*)&dstp[8] = *(const half8*)&F[qrow][dseg + 8];
}

extern "C" void kernel_launch(void* const* d_in, const int* in_sizes, int n_in,
                              void* d_out, int out_size, void* d_ws, size_t ws_size,
                              hipStream_t stream) {
    const float* q  = (const float*)d_in[0];
    const float* k  = (const float*)d_in[1];
    const float* v  = (const float*)d_in[2];
    const float* Wq = (const float*)d_in[3];
    const float* bq = (const float*)d_in[4];
    const float* Wk = (const float*)d_in[5];
    const float* bk = (const float*)d_in[6];
    const float* Wv = (const float*)d_in[7];
    const float* bv = (const float*)d_in[8];
    const float* Wo = (const float*)d_in[9];
    const float* bo = (const float*)d_in[10];
    float* out = (float*)d_out;

    __half* ws = (__half*)d_ws;
    const size_t NE = (size_t)B_ * S_ * D_;     // 4,194,304
    __half* qf   = ws;
    __half* kf   = ws + NE;
    __half* vf   = ws + 2 * NE;
    __half* qhf  = ws + 3 * NE;
    __half* khf  = ws + 4 * NE;
    __half* vht  = ws + 5 * NE;
    __half* attf = ws + 6 * NE;
    __half* Wtq  = ws + 7 * NE;
    __half* Wtk  = Wtq + (size_t)D_ * D_;
    __half* Wtv  = Wtk + (size_t)D_ * D_;
    __half* Wto  = Wtv + (size_t)D_ * D_;

    const dim3 blk(256);
    prep<<<dim3((unsigned)(NE / 8 / 256), 1, 4), blk, 0, stream>>>(
        q, k, v, qf, kf, vf, Wq, Wk, Wv, Wo, Wtq, Wtk, Wtv, Wto);

    gemm_proj<<<dim3(D_ / 128, (B_ * S_) / 128, 3), blk, 73728, stream>>>(
        qf, kf, vf, Wtq, Wtk, Wtv, bq, bk, bv, qhf, khf, vht);

    attn_f16<<<dim3(S_ / 128, B_ * H_), dim3(512), 0, stream>>>(qhf, khf, vht, attf);

    gemm_final<<<dim3(D_ / 128, (B_ * S_) / 128), blk, 73728, stream>>>(attf, Wto, bo, out);
}

// Round 8
// 222.358 us; speedup vs baseline: 1.0944x; 1.0016x over previous
//
#include <hip/hip_runtime.h>
#include <hip/hip_fp16.h>
#include <cstddef>

// ---------------------------------------------------------------------------
// CrossAttention, f16 MFMA, round 16.
//   B=2, Sq=Sk=2048, D=1024, H=16, Dh=64
// r15 post-mortem: XCD swizzle cut FETCH 101->30MB but gemm_proj stayed 49us
// -> not fetch-bound; reg-staged K-loop's VALU/latency is the cost (m151:
// reg-staging 646 TF vs global_load_lds 874 TF at 128^2 tile).
// r16: gemm_core -> m97 structure: global_load_lds w16 staging (LDS linear
// [128][64], dest = wave-base + lane*16 per T21), 2 barriers/K-step,
// single-buffered 32KB staging (34816B total with epilogue overlay).
// Bank conflicts rise (linear rows, m97's known 16-way pattern) -- accepted,
// T2 swizzle is measured-null in 2-phase structures (m252).
// attn (r14/r15 structure) and prep unchanged; XCD swizzles kept.
// Layouts (32x32x16): A/B [idx=lane&31][k=(lane>>5)*8+j];
//   C/D col=lane&31, row=(reg&3)+8*(reg>>2)+4*(lane>>5)  [m74/m101].
// P repack: P0=pk(s0,s1) P1=pk(s2,s3) P2=pk(s4,s5) P3=pk(s6,s7);
//   swap(P0,P2), swap(P1,P3) -> B-frag words [P0,P1,P2,P3]. (r13-verified)
// ---------------------------------------------------------------------------

#define B_   2
#define S_   2048
#define D_   1024
#define H_   16
#define DH_  64

typedef _Float16 half8 __attribute__((ext_vector_type(8)));
typedef _Float16 half4 __attribute__((ext_vector_type(4)));
typedef _Float16 half2v __attribute__((ext_vector_type(2)));
typedef float floatx4 __attribute__((ext_vector_type(4)));
typedef float floatx16 __attribute__((ext_vector_type(16)));
typedef int intx4 __attribute__((ext_vector_type(4)));

#define MFMA32(a, b, c) __builtin_amdgcn_mfma_f32_16x16x32_f16((a), (b), (c), 0, 0, 0)
#define MFMA3216(a, b, c) __builtin_amdgcn_mfma_f32_32x32x16_f16((a), (b), (c), 0, 0, 0)

#if __has_builtin(__builtin_amdgcn_fdot2)
#define LP_FDOT2 1
#else
#define LP_FDOT2 0
#endif

#define GLD_AS(p) ((const __attribute__((address_space(1))) void*)(p))
#define LDS_AS(p) ((__attribute__((address_space(3))) void*)(p))

// exchange: newA = {A.lo32, B.lo32}, newB = {A.hi32, B.hi32}
__device__ __forceinline__ void half_swap(int& a, int& b, const int hi) {
#if __has_builtin(__builtin_amdgcn_permlane32_swap)
    (void)hi;
    auto r = __builtin_amdgcn_permlane32_swap(a, b, false, false);
    a = r[0]; b = r[1];
#else
    const int ax = __shfl_xor(a, 32, 64), bx = __shfl_xor(b, 32, 64);
    const int na = hi ? bx : a;
    b = hi ? b : ax;
    a = na;
#endif
}

// ---- fused: fp32->f16 cvt for q/k/v (z<3) + W transpose x4 (z==3) ----
__global__ __launch_bounds__(256) void prep(
    const float* __restrict__ q, const float* __restrict__ k,
    const float* __restrict__ v,
    __half* __restrict__ qf, __half* __restrict__ kf, __half* __restrict__ vf,
    const float* __restrict__ Wq, const float* __restrict__ Wk,
    const float* __restrict__ Wv, const float* __restrict__ Wo,
    __half* __restrict__ Wtq, __half* __restrict__ Wtk,
    __half* __restrict__ Wtv, __half* __restrict__ Wto)
{
    __shared__ __align__(16) __half T[64][72];
    const int tid = threadIdx.x;
    const int z = blockIdx.z;
    if (z < 3) {
        const float* srcs[3] = {q, k, v};
        __half* dsts[3] = {qf, kf, vf};
        const int i = blockIdx.x * 256 + tid;
        const float4* s = (const float4*)srcs[z];
        const float4 a = s[2 * i], b = s[2 * i + 1];
        half8 h;
        h[0] = (_Float16)a.x; h[1] = (_Float16)a.y; h[2] = (_Float16)a.z; h[3] = (_Float16)a.w;
        h[4] = (_Float16)b.x; h[5] = (_Float16)b.y; h[6] = (_Float16)b.z; h[7] = (_Float16)b.w;
        *(half8*)&dsts[z][(size_t)i * 8] = h;
        return;
    }
    if (blockIdx.x >= 256) return;
    const float* Ws[4] = {Wq, Wk, Wv, Wo};
    __half* Wts[4] = {Wtq, Wtk, Wtv, Wto};
    const int n0 = (blockIdx.x & 15) * 64, k0 = (blockIdx.x >> 4) * 64;
    for (int w = 0; w < 4; ++w) {
        const float* W = Ws[w];
        __half* Wt = Wts[w];
        #pragma unroll
        for (int p = 0; p < 4; ++p) {
            const int c = tid + p * 256;
            const int kr = c >> 4, nc = (c & 15) * 4;
            const float4 a = *(const float4*)&W[(size_t)(k0 + kr) * D_ + n0 + nc];
            T[nc + 0][kr] = __float2half(a.x);
            T[nc + 1][kr] = __float2half(a.y);
            T[nc + 2][kr] = __float2half(a.z);
            T[nc + 3][kr] = __float2half(a.w);
        }
        __syncthreads();
        #pragma unroll
        for (int p = 0; p < 2; ++p) {
            const int c = tid + p * 256;
            const int nr = c >> 3, kc = (c & 7) * 8;
            *(half8*)&Wt[(size_t)(n0 + nr) * D_ + k0 + kc] = *(const half8*)&T[nr][kc];
        }
        __syncthreads();
    }
}

// ---- 128x128 f16 GEMM core, m97-style global_load_lds staging (r16) ----
// Static LDS 34816B: staging As[128][64]+Bs[128][64] linear (32KB);
// epilogue overlays Ct[128][136] (34816B). 2 barriers per K-step.
// mode 0: dst f16 scatter [B,H,S,Dh] * oscale (coalesced via LDS transpose)
// mode 1: dst fp32 [M][1024] direct
// mode 2: dst f16 transposed [B,H,Dh,S] (coalesced via LDS transpose)
__device__ __forceinline__ void gemm_core(
    const __half* __restrict__ A, const __half* __restrict__ Bt,
    const float* __restrict__ bias, void* __restrict__ dst,
    const int mode, const float oscale, const int m0, const int n0)
{
    __shared__ __align__(16) char gsm[34816];
    __half* Asl = (__half*)gsm;            // [128][64] linear
    __half* Bsl = (__half*)(gsm + 16384);  // [128][64] linear

    const int tid = threadIdx.x;
    const int lane = tid & 63, wv = tid >> 6;
    const int quad = lane >> 4, lr = lane & 15;
    const int wm0 = (wv >> 1) * 64, wn0 = (wv & 1) * 64;

    floatx4 acc[4][4];
    #pragma unroll
    for (int i = 0; i < 4; ++i)
        #pragma unroll
        for (int j = 0; j < 4; ++j)
            acc[i][j] = (floatx4){0.f, 0.f, 0.f, 0.f};

    // staging source: slot c = wv*256 + p*64 + lane covers LDS bytes c*16..+15
    //   row = c>>3 = wv*32 + p*8 + (lane>>3), col halves = (c&7)*8 = (lane&7)*8
    const int rowb = wv * 32 + (lane >> 3);
    const int colb = (lane & 7) * 8;
    const __half* gA = A  + (size_t)(m0 + rowb) * D_ + colb;
    const __half* gB = Bt + (size_t)(n0 + rowb) * D_ + colb;

    for (int k0 = 0; k0 < D_; k0 += 64) {
        __syncthreads();                  // prior compute's LDS reads done
        #pragma unroll
        for (int p = 0; p < 4; ++p) {
            __builtin_amdgcn_global_load_lds(
                GLD_AS(gA + (size_t)p * 8 * D_),
                LDS_AS(gsm + (wv * 4 + p) * 1024), 16, 0, 0);
            __builtin_amdgcn_global_load_lds(
                GLD_AS(gB + (size_t)p * 8 * D_),
                LDS_AS(gsm + 16384 + (wv * 4 + p) * 1024), 16, 0, 0);
        }
        gA += 64; gB += 64;
        __syncthreads();                  // staged tile visible (vmcnt drained)

        __builtin_amdgcn_s_setprio(1);
        #pragma unroll
        for (int ks = 0; ks < 2; ++ks) {
            const int ko = quad * 8 + ks * 32;
            half8 af[4], bf[4];
            #pragma unroll
            for (int i = 0; i < 4; ++i)
                af[i] = *(const half8*)&Asl[(wm0 + i * 16 + lr) * 64 + ko];
            #pragma unroll
            for (int j = 0; j < 4; ++j)
                bf[j] = *(const half8*)&Bsl[(wn0 + j * 16 + lr) * 64 + ko];
            #pragma unroll
            for (int i = 0; i < 4; ++i)
                #pragma unroll
                for (int j = 0; j < 4; ++j)
                    acc[i][j] = MFMA32(af[i], bf[j], acc[i][j]);
        }
        __builtin_amdgcn_s_setprio(0);
    }

    if (mode == 1) {
        float* out = (float*)dst;
        #pragma unroll
        for (int i = 0; i < 4; ++i) {
            #pragma unroll
            for (int j = 0; j < 4; ++j) {
                const int col = n0 + wn0 + j * 16 + lr;
                const float bval = bias[col];
                #pragma unroll
                for (int r = 0; r < 4; ++r) {
                    const int m = m0 + wm0 + i * 16 + quad * 4 + r;
                    out[(size_t)m * D_ + col] = acc[i][j][r] + bval;
                }
            }
        }
        return;
    }

    // ---- LDS transpose epilogue (modes 0 and 2) ----
    __syncthreads();                      // all waves' staging reads done
    __half (*Ct)[136] = (__half(*)[136])gsm;
    #pragma unroll
    for (int i = 0; i < 4; ++i) {
        #pragma unroll
        for (int j = 0; j < 4; ++j) {
            const int nl = wn0 + j * 16 + lr;
            const float bval = bias[n0 + nl];
            #pragma unroll
            for (int r = 0; r < 4; ++r) {
                const int ml = wm0 + i * 16 + quad * 4 + r;
                const _Float16 hv = (_Float16)((acc[i][j][r] + bval) * oscale);
                if (mode == 0) Ct[ml][nl] = hv;
                else           Ct[nl][ml] = hv;
            }
        }
    }
    __syncthreads();
    __half* oh = (__half*)dst;
    #pragma unroll
    for (int p = 0; p < 8; ++p) {
        const int row = (tid >> 4) + p * 16;
        const int cs  = (tid & 15) * 8;
        const half8 vls = *(const half8*)&Ct[row][cs];
        if (mode == 0) {
            const int m = m0 + row, col = n0 + cs;
            const int b = m >> 11, s = m & (S_ - 1);
            const int h = col >> 6, d = col & 63;
            *(half8*)&oh[(((size_t)(b * H_ + h) * S_ + s) << 6) + d] = vls;
        } else {
            const int col = n0 + row, m = m0 + cs;
            const int b = m >> 11, s = m & (S_ - 1);
            const int h = col >> 6, d = col & 63;
            *(half8*)&oh[((size_t)(b * H_ + h) * DH_ + d) * S_ + s] = vls;
        }
    }
}

// z=0: Q (scatter, *0.125*log2e for exp2 softmax), z=1: K, z=2: V (transposed)
// XCD swizzle: grid (8,32,3)=768 blocks, 96/XCD contiguous (bijective).
__global__ __launch_bounds__(256) void gemm_proj(
    const __half* __restrict__ qf, const __half* __restrict__ kf,
    const __half* __restrict__ vf,
    const __half* __restrict__ Wtq, const __half* __restrict__ Wtk,
    const __half* __restrict__ Wtv,
    const float* __restrict__ bq, const float* __restrict__ bk,
    const float* __restrict__ bv,
    __half* __restrict__ qhf, __half* __restrict__ khf, __half* __restrict__ vht)
{
    const int flat = blockIdx.x + (blockIdx.y << 3) + (blockIdx.z << 8);
    const int wid = (flat & 7) * 96 + (flat >> 3);
    const int z = wid >> 8;
    const int rem = wid & 255;
    const int m0 = (rem >> 3) * 128, n0 = (rem & 7) * 128;

    const __half* As[3] = {qf, kf, vf};
    const __half* Bts[3] = {Wtq, Wtk, Wtv};
    const float* bs[3] = {bq, bk, bv};
    __half* ds[3] = {qhf, khf, vht};
    gemm_core(As[z], Bts[z], bs[z], ds[z], z == 2 ? 2 : 0,
              z == 0 ? 0.1803368801111244f : 1.0f, m0, n0);
}

// XCD swizzle: grid (8,32)=256 blocks, 32/XCD contiguous.
__global__ __launch_bounds__(256) void gemm_final(
    const __half* __restrict__ attf, const __half* __restrict__ Wto,
    const float* __restrict__ bo, float* __restrict__ out)
{
    const int flat = blockIdx.x + (blockIdx.y << 3);
    const int wid = (flat & 7) * 32 + (flat >> 3);
    const int m0 = (wid >> 3) * 128, n0 = (wid & 7) * 128;
    gemm_core(attf, Wto, bo, out, 1, 1.0f, m0, n0);
}

// ---- flash attention, 32x32 MFMA, QBLK=128, 512 threads (8 waves) ----
// qhf/khf: [B,H,S,64] f16 (Q pre-scaled 0.125*log2e). vht: [B,H,64,S].
// Wave wv: kb=wv>>2 (k-band 32), qb=wv&3 (q-band 32 of 128). Per 64-k tile
// per wave: 4 QK MFMA -> 16 exp2 -> 8 cvt_pkrtz + 4 permlane32_swap ->
// 4 PV MFMA; lp row-sum via 8 fdot2 on packed P AFTER PV issue.
// XCD swizzle: grid (16,32)=512 blocks, 64/XCD = 4 complete heads' K/V.
__global__ __launch_bounds__(512, 4) void attn_f16(
    const __half* __restrict__ qhf, const __half* __restrict__ khf,
    const __half* __restrict__ vht, __half* __restrict__ attf)
{
    __shared__ __align__(16) char smem[36864];

    const int tid = threadIdx.x;
    const int lane = tid & 63, wv = tid >> 6;
    const int l31 = lane & 31, hi = lane >> 5;
    const int kb = wv >> 2, qb = wv & 3;
    const int flat = blockIdx.x + (blockIdx.y << 4);
    const int wid = ((flat & 7) << 6) + (flat >> 3);
    const int bh = wid >> 4;
    const int q0 = (wid & 15) * 128;
    const size_t hbase = (size_t)bh * S_ * DH_;

    // ---- Q B-frags [idx=q=l31][k(d)=hi*8+j] per 16-d slice, from global ----
    half8 qB[4];
    #pragma unroll
    for (int ds = 0; ds < 4; ++ds)
        qB[ds] = *(const half8*)&qhf[hbase
            + (size_t)(q0 + qb * 32 + l31) * DH_ + ds * 16 + hi * 8];

    float lp0 = 0.f, lp1 = 0.f;
#if !LP_FDOT2
    float lp2 = 0.f, lp3 = 0.f;
#endif
    floatx16 O[2];
    #pragma unroll
    for (int i = 0; i < 16; ++i) { O[0][i] = 0.f; O[1][i] = 0.f; }

    // ---- staging mapping (512 thr): one K + one V half8 per thread ----
    const int srow = tid >> 3, sseg = (tid & 7) * 8;
    const __half* kg = khf + hbase + (size_t)srow * DH_ + sseg;  // += 64*DH_/tile
    const __half* vg = vht + hbase + (size_t)srow * S_ + sseg;   // += 64/tile

    // ---- stage tile 0 directly into buf0 ----
    {
        __half (*K0)[72] = (__half(*)[72])smem;
        __half (*V0)[72] = (__half(*)[72])(smem + 9216);
        *(half8*)&K0[srow][sseg] = *(const half8*)kg;
        *(half8*)&V0[srow][sseg] = *(const half8*)vg;
    }
    // ---- prefetch tile 1 into registers ----
    kg += 64 * DH_; vg += 64;
    half8 pk = *(const half8*)kg;
    half8 pv = *(const half8*)vg;
    __syncthreads();                       // tile 0 visible

    const half2v one2 = {(_Float16)1.0f, (_Float16)1.0f};

    for (int kt = 0; kt < S_; kt += 64) {
        const int cb = (kt >> 6) & 1;
        __half (*Ks)[72] = (__half(*)[72])(smem + cb * 18432);
        __half (*Vs)[72] = (__half(*)[72])(smem + cb * 18432 + 9216);
        __half (*Kn)[72] = (__half(*)[72])(smem + (cb ^ 1) * 18432);
        __half (*Vn)[72] = (__half(*)[72])(smem + (cb ^ 1) * 18432 + 9216);

        // write tile t+1 into the other buffer (overlaps compute reads)
        if (kt + 64 < S_) {
            *(half8*)&Kn[srow][sseg] = pk;
            *(half8*)&Vn[srow][sseg] = pv;
            if (kt + 128 < S_) {           // issue t+2 loads; fly during compute
                kg += 64 * DH_; vg += 64;
                pk = *(const half8*)kg;
                pv = *(const half8*)vg;
            }
        }

        // ---- S^T = K Q^T : 32k (band kb) x 32q (band qb), K-dim = d ----
        floatx16 s;
        #pragma unroll
        for (int i = 0; i < 16; ++i) s[i] = 0.f;
        __builtin_amdgcn_s_setprio(1);
        #pragma unroll
        for (int ds = 0; ds < 4; ++ds) {
            const half8 aK = *(const half8*)&Ks[kb * 32 + l31][ds * 16 + hi * 8];
            s = MFMA3216(aK, qB[ds], s);
        }
        __builtin_amdgcn_s_setprio(0);

        // ---- P^T = exp2(S^T) ----
        #pragma unroll
        for (int r = 0; r < 16; ++r) {
            const float e = __builtin_amdgcn_exp2f(s[r]);
#if !LP_FDOT2
            (r & 2) ? ((r & 1) ? (lp3 += e) : (lp2 += e))
                    : ((r & 1) ? (lp1 += e) : (lp0 += e));
#endif
            s[r] = e;
        }

        // ---- pack to PV B-frags [idx=q][k=hi*8+j] per 16-k slice ----
        half8 pB[2];
        int PW[2][4];
        #pragma unroll
        for (int ks = 0; ks < 2; ++ks) {
            int P0 = __builtin_bit_cast(int, __builtin_amdgcn_cvt_pkrtz(s[ks * 8 + 0], s[ks * 8 + 1]));
            int P1 = __builtin_bit_cast(int, __builtin_amdgcn_cvt_pkrtz(s[ks * 8 + 2], s[ks * 8 + 3]));
            int P2 = __builtin_bit_cast(int, __builtin_amdgcn_cvt_pkrtz(s[ks * 8 + 4], s[ks * 8 + 5]));
            int P3 = __builtin_bit_cast(int, __builtin_amdgcn_cvt_pkrtz(s[ks * 8 + 6], s[ks * 8 + 7]));
            half_swap(P0, P2, hi);
            half_swap(P1, P3, hi);
            PW[ks][0] = P0; PW[ks][1] = P1; PW[ks][2] = P2; PW[ks][3] = P3;
            const intx4 w = {P0, P1, P2, P3};
            pB[ks] = __builtin_bit_cast(half8, w);
        }

        // ---- O^T += V^T P^T over wave's 32-k band ----
        __builtin_amdgcn_s_setprio(1);
        #pragma unroll
        for (int db = 0; db < 2; ++db)
            #pragma unroll
            for (int ks = 0; ks < 2; ++ks) {
                const half8 aV = *(const half8*)&Vs[db * 32 + l31][kb * 32 + ks * 16 + hi * 8];
                O[db] = MFMA3216(aV, pB[ks], O[db]);
            }
        __builtin_amdgcn_s_setprio(0);

#if LP_FDOT2
        // ---- lp row-sum from packed P (VALU-free window: MFMA pipe busy) ----
        #pragma unroll
        for (int ks = 0; ks < 2; ++ks) {
            lp0 = __builtin_amdgcn_fdot2(__builtin_bit_cast(half2v, PW[ks][0]), one2, lp0, false);
            lp1 = __builtin_amdgcn_fdot2(__builtin_bit_cast(half2v, PW[ks][1]), one2, lp1, false);
            lp0 = __builtin_amdgcn_fdot2(__builtin_bit_cast(half2v, PW[ks][2]), one2, lp0, false);
            lp1 = __builtin_amdgcn_fdot2(__builtin_bit_cast(half2v, PW[ks][3]), one2, lp1, false);
        }
#endif

        __syncthreads();   // t+1 writes visible; buf reads done before t+2 overwrite
    }

    // ---- epilogue: 2-way k-band reduce + softmax normalize, 128 q rows ----
    float (*R)[132] = (float(*)[132])smem;            // [64 d][128 q(+4)] f32
    float* Lred = (float*)(smem + 33792);             // [2][128] f32

#if LP_FDOT2
    float lp = lp0 + lp1;
#else
    float lp = (lp0 + lp1) + (lp2 + lp3);
#endif
    lp += __shfl_xor(lp, 32, 64);                     // combine hi/lo (same q)
    const int qg = qb * 32 + l31;
    if (lane < 32) Lred[kb * 128 + qg] = lp;
    if (kb == 1) {
        #pragma unroll
        for (int db = 0; db < 2; ++db)
            #pragma unroll
            for (int r = 0; r < 16; ++r) {
                const int d = db * 32 + (r & 3) + 8 * (r >> 2) + 4 * hi;
                R[d][qg] = O[db][r];
            }
    }
    __syncthreads();
    if (kb == 0) {
        const float il = 1.0f / (Lred[qg] + Lred[128 + qg]);
        #pragma unroll
        for (int db = 0; db < 2; ++db)
            #pragma unroll
            for (int r = 0; r < 16; ++r) {
                const int d = db * 32 + (r & 3) + 8 * (r >> 2) + 4 * hi;
                O[db][r] = (O[db][r] + R[d][qg]) * il;
            }
    }
    __syncthreads();
    __half (*F)[72] = (__half(*)[72])smem;            // [128 q][64 d] f16
    if (kb == 0) {
        #pragma unroll
        for (int db = 0; db < 2; ++db)
            #pragma unroll
            for (int t = 0; t < 4; ++t) {
                half4 hv;
                #pragma unroll
                for (int r = 0; r < 4; ++r) hv[r] = (_Float16)O[db][t * 4 + r];
                *(half4*)&F[qg][db * 32 + t * 8 + hi * 4] = hv;
            }
    }
    __syncthreads();

    const int b = bh >> 4, h = bh & 15;
    const int qrow = tid >> 2, dseg = (tid & 3) * 16;
    __half* dstp = &attf[(((size_t)(b * S_ + q0 + qrow)) << 10) + h * DH_ + dseg];
    *(half8*)&dstp[0] = *(const half8*)&F[qrow][dseg];
    *(half8*)&dstp[8] = *(const half8*)&F[qrow][dseg + 8];
}

extern "C" void kernel_launch(void* const* d_in, const int* in_sizes, int n_in,
                              void* d_out, int out_size, void* d_ws, size_t ws_size,
                              hipStream_t stream) {
    const float* q  = (const float*)d_in[0];
    const float* k  = (const float*)d_in[1];
    const float* v  = (const float*)d_in[2];
    const float* Wq = (const float*)d_in[3];
    const float* bq = (const float*)d_in[4];
    const float* Wk = (const float*)d_in[5];
    const float* bk = (const float*)d_in[6];
    const float* Wv = (const float*)d_in[7];
    const float* bv = (const float*)d_in[8];
    const float* Wo = (const float*)d_in[9];
    const float* bo = (const float*)d_in[10];
    float* out = (float*)d_out;

    __half* ws = (__half*)d_ws;
    const size_t NE = (size_t)B_ * S_ * D_;     // 4,194,304
    __half* qf   = ws;
    __half* kf   = ws + NE;
    __half* vf   = ws + 2 * NE;
    __half* qhf  = ws + 3 * NE;
    __half* khf  = ws + 4 * NE;
    __half* vht  = ws + 5 * NE;
    __half* attf = ws + 6 * NE;
    __half* Wtq  = ws + 7 * NE;
    __half* Wtk  = Wtq + (size_t)D_ * D_;
    __half* Wtv  = Wtk + (size_t)D_ * D_;
    __half* Wto  = Wtv + (size_t)D_ * D_;

    const dim3 blk(256);
    prep<<<dim3((unsigned)(NE / 8 / 256), 1, 4), blk, 0, stream>>>(
        q, k, v, qf, kf, vf, Wq, Wk, Wv, Wo, Wtq, Wtk, Wtv, Wto);

    gemm_proj<<<dim3(D_ / 128, (B_ * S_) / 128, 3), blk, 0, stream>>>(
        qf, kf, vf, Wtq, Wtk, Wtv, bq, bk, bv, qhf, khf, vht);

    attn_f16<<<dim3(S_ / 128, B_ * H_), dim3(512), 0, stream>>>(qhf, khf, vht, attf);

    gemm_final<<<dim3(D_ / 128, (B_ * S_) / 128), blk, 0, stream>>>(attf, Wto, bo, out);
}